// Round 15
// baseline (427.650 us; speedup 1.0000x reference)
//
#include <hip/hip_runtime.h>
#include <hip/hip_bf16.h>
#include <stdint.h>

typedef uint16_t u16;
typedef __attribute__((ext_vector_type(8))) __bf16 bf16x8;
typedef __attribute__((ext_vector_type(4))) float f32x4;
typedef __attribute__((ext_vector_type(4))) u16 u16x4;

// Problem constants
#define BSZ   256
#define NN    512
#define TT    12
#define FF    12
#define HID   1536
#define INSZ  6144    // N*F = LSTM input size
#define GATES 6144    // 4*HID
#define MROWS 3072    // FF*BSZ rows of the hoisted input GEMM

static __device__ __forceinline__ u16 f2bf(float x) {
  uint32_t u = __builtin_bit_cast(uint32_t, x);
  u += 0x7fffu + ((u >> 16) & 1u);   // RNE
  return (u16)(u >> 16);
}

static __device__ __forceinline__ float sigm(float x) {
  return 1.0f / (1.0f + expf(-x));
}

// ---------------- fp32 -> bf16 convert + gate-interleave row permute ----------------
// out row' = 4*(r%HID) + r/HID  (orig row r = g*HID + j  ->  row' = 4j+g)
__global__ void cvt_perm(const float* __restrict__ in, u16* __restrict__ out,
                         int ncol4) {
  long idx = (long)blockIdx.x * blockDim.x + threadIdx.x;   // r*ncol4 + c4
  int r  = (int)(idx / ncol4);
  int c4 = (int)(idx - (long)r * ncol4);
  int rp = ((r % HID) << 2) + r / HID;
  float4 v = ((const float4*)in)[idx];
  u16x4 w = { f2bf(v.x), f2bf(v.y), f2bf(v.z), f2bf(v.w) };
  ((u16x4*)out)[(size_t)rp * ncol4 + c4] = w;
}

// ---------------- pack X: 4 k's per thread -> coalesced u16x4 writes ----------------
__global__ void pack_x4(const float* __restrict__ X, u16* __restrict__ Ax) {
  int idx = blockIdx.x * blockDim.x + threadIdx.x;   // (b, k4), k4 in [0,1536)
  int b  = idx / (INSZ / 4);
  int k4 = idx - b * (INSZ / 4);
  const float* xp = X + (size_t)b * (INSZ * FF) + (size_t)k4 * (4 * FF);
  float4 v[12];   // 48 floats = [kk 0..3][f 0..11]
#pragma unroll
  for (int j = 0; j < 12; ++j) v[j] = ((const float4*)xp)[j];
  const float* vf = (const float*)v;
#pragma unroll
  for (int f = 0; f < FF; ++f) {
    u16x4 w = { f2bf(vf[0 * FF + f]), f2bf(vf[1 * FF + f]),
                f2bf(vf[2 * FF + f]), f2bf(vf[3 * FF + f]) };
    *(u16x4*)&Ax[(size_t)(f * BSZ + b) * INSZ + k4 * 4] = w;
  }
}

// =====================================================================
// Deep-pipelined bf16 GEMM (R13: one-group-ahead read skew, 186 us,
// MfmaUtil 57%). Tile 192x384, BK=64, 8 waves, 2 barriers/K-tile.
// =====================================================================
#define BM8 192
#define BN8 384
#define LDSA_SZ 24576
#define LDSB_SZ 49152
#define LDS_TOTAL (2 * (LDSA_SZ + LDSB_SZ))   // 147456

#define GLL(src, dst)                                                          \
  __builtin_amdgcn_global_load_lds(                                            \
      (const __attribute__((address_space(1))) void*)(src),                    \
      (__attribute__((address_space(3))) void*)(dst), 16, 0, 0)

#define SBAR() asm volatile("s_barrier" ::: "memory")
#define SCHED_FENCE_DS() __builtin_amdgcn_sched_barrier(0x7F)
#define WAIT_LGKM0()                                                           \
  do {                                                                         \
    asm volatile("s_waitcnt lgkmcnt(0)" ::: "memory");                         \
    __builtin_amdgcn_sched_barrier(0);                                         \
  } while (0)

#define MFMA9(AF, BF, RO, CO)                                                  \
  do {                                                                         \
    __builtin_amdgcn_s_setprio(1);                                             \
    _Pragma("unroll") for (int i = 0; i < 3; ++i)                              \
        _Pragma("unroll") for (int j = 0; j < 3; ++j)                          \
            acc[RO + i][CO + j] = __builtin_amdgcn_mfma_f32_16x16x32_bf16(     \
                AF[i], BF[j], acc[RO + i][CO + j], 0, 0, 0);                   \
    __builtin_amdgcn_s_setprio(0);                                             \
  } while (0)

__global__ __launch_bounds__(512, 1) void gemm8p(
    const u16* __restrict__ A, const u16* __restrict__ Bt,
    const float* __restrict__ bi, const float* __restrict__ bh,
    float* __restrict__ C, int M, int N, int K) {
  extern __shared__ __align__(16) char lds[];
  const int tid  = threadIdx.x;
  const int lane = tid & 63;
  const int wid  = tid >> 6;
  const int wr   = wid >> 2;
  const int wc   = wid & 3;

  const int nbx  = N / BN8;
  const int cpx  = gridDim.x >> 3;
  const int orig = blockIdx.x;
  const int wgid = (orig & 7) * cpx + (orig >> 3);
  const int m0   = (wgid / nbx) * BM8;
  const int n0   = (wgid % nbx) * BN8;

  const int fr    = lane & 15;
  const int kb    = (lane >> 4) << 4;
  const int swz   = (fr & 7) << 4;
  const int colp0 = kb ^ swz;
  const int colp1 = (64 | kb) ^ swz;

  const int srow = tid >> 3;
  const int scb  = ((tid & 7) << 4) ^ ((srow & 7) << 4);
  const u16* gA = A  + (size_t)(m0 + srow) * K + (scb >> 1);
  const u16* gB = Bt + (size_t)(n0 + srow) * K + (scb >> 1);
  const int wdst = wid << 10;

  char* ldsA = lds;
  char* ldsB = lds + 2 * LDSA_SZ;
  char* aRowB = ldsA + (wr * 96 + fr) * 128;
  char* bRowB = ldsB + (wc * 96 + fr) * 128;

  f32x4 acc[6][6] = {};
  const int NT = K >> 6;

#pragma unroll
  for (int c = 0; c < 3; ++c) GLL(gA + (size_t)c * 64 * K, ldsA + c * 8192 + wdst);
#pragma unroll
  for (int c = 0; c < 6; ++c) GLL(gB + (size_t)c * 64 * K, ldsB + c * 8192 + wdst);

  for (int t = 0; t < NT; ++t) {
    const int p = t & 1;
    char* aRow = aRowB + p * LDSA_SZ;
    char* bRow = bRowB + p * LDSB_SZ;
    char* An = ldsA + (p ^ 1) * LDSA_SZ;
    char* Bn = ldsB + (p ^ 1) * LDSB_SZ;
    const u16* gAn = gA + (size_t)(t + 1) * 64;
    const u16* gBn = gB + (size_t)(t + 1) * 64;
    const bool pf = (t + 1 < NT);

    bf16x8 a0[2][3], a1[2][3], b0[2][3], b1[2][3];

    if (pf) {
#pragma unroll
      for (int c = 0; c < 3; ++c) GLL(gAn + (size_t)c * 64 * K, An + c * 8192 + wdst);
      asm volatile("s_waitcnt vmcnt(3)" ::: "memory");
    } else {
      asm volatile("s_waitcnt vmcnt(0)" ::: "memory");
    }
    SBAR();

    // ---- p0: read a0k0 + b0k0
#pragma unroll
    for (int i = 0; i < 3; ++i) {
      a0[0][i] = *(const bf16x8*)(aRow + i * 2048 + colp0);
      b0[0][i] = *(const bf16x8*)(bRow + i * 2048 + colp0);
    }
    // ---- p1: read b1k0 ; q00k0
#pragma unroll
    for (int i = 0; i < 3; ++i) b1[0][i] = *(const bf16x8*)(bRow + (3 + i) * 2048 + colp0);
    MFMA9(a0[0], b0[0], 0, 0);
    if (pf) {
      GLL(gBn + (size_t)0 * 64 * K, Bn + 0 * 8192 + wdst);
      GLL(gBn + (size_t)1 * 64 * K, Bn + 1 * 8192 + wdst);
    }
    SCHED_FENCE_DS();

    // ---- p2: read a1k0 ; q01k0
#pragma unroll
    for (int i = 0; i < 3; ++i) a1[0][i] = *(const bf16x8*)(aRow + (3 + i) * 2048 + colp0);
    MFMA9(a0[0], b1[0], 0, 3);
    if (pf) {
      GLL(gBn + (size_t)2 * 64 * K, Bn + 2 * 8192 + wdst);
      GLL(gBn + (size_t)3 * 64 * K, Bn + 3 * 8192 + wdst);
    }
    SCHED_FENCE_DS();

    // ---- p3: read a0k1 ; q11k0
#pragma unroll
    for (int i = 0; i < 3; ++i) a0[1][i] = *(const bf16x8*)(aRow + i * 2048 + colp1);
    MFMA9(a1[0], b1[0], 3, 3);
    if (pf) {
      GLL(gBn + (size_t)4 * 64 * K, Bn + 4 * 8192 + wdst);
      GLL(gBn + (size_t)5 * 64 * K, Bn + 5 * 8192 + wdst);
    }
    SCHED_FENCE_DS();

    // ---- p4: read b0k1 ; q10k0
#pragma unroll
    for (int i = 0; i < 3; ++i) b0[1][i] = *(const bf16x8*)(bRow + i * 2048 + colp1);
    MFMA9(a1[0], b0[0], 3, 0);
    SCHED_FENCE_DS();

    // ---- p5: read b1k1 ; q00k1
#pragma unroll
    for (int i = 0; i < 3; ++i) b1[1][i] = *(const bf16x8*)(bRow + (3 + i) * 2048 + colp1);
    MFMA9(a0[1], b0[1], 0, 0);
    SCHED_FENCE_DS();

    // ---- p6: read a1k1 ; q01k1
#pragma unroll
    for (int i = 0; i < 3; ++i) a1[1][i] = *(const bf16x8*)(aRow + (3 + i) * 2048 + colp1);
    MFMA9(a0[1], b1[1], 0, 3);
    SCHED_FENCE_DS();

    // ---- p7: q11k1 ; q10k1
    MFMA9(a1[1], b1[1], 3, 3);
    MFMA9(a1[1], b0[1], 3, 0);

    SBAR();
  }

  const int r0 = (lane >> 4) << 2;
  const int cc = lane & 15;
#pragma unroll
  for (int j = 0; j < 6; ++j) {
    const int col = n0 + wc * 96 + j * 16 + cc;          // interleaved position
    const int oc  = (col & 3) * HID + (col >> 2);        // original gate index
    const float bv = bi[oc] + bh[oc];
#pragma unroll
    for (int i = 0; i < 6; ++i) {
      const size_t rbase = (size_t)(m0 + wr * 96 + i * 16 + r0) * N + col;
#pragma unroll
      for (int r = 0; r < 4; ++r)
        C[rbase + (size_t)r * N] = acc[i][j][r] + bv;
    }
  }
}

// =====================================================================
// Fused step (R15: 32x64 tile -> 768 blocks = 3/CU = 12 waves/CU TLP,
// 2x the latency-hiding of R14's 384-block config). BK=64, dbuf 24KB,
// vmcnt(3). XCD mapping: xcd=orig&7 owns n-tiles [12x,12x+12) x 8
// m-tiles (Whhb panel set 2.4MB/XCD stays L2-hot across steps).
// Gate-interleaved layout -> cell in epilogue. hbf double-buffered.
// =====================================================================
__global__ __launch_bounds__(256, 4) void gemm_cell(
    const u16* __restrict__ hbf_in,    // (256 x 1536) bf16 h(t-1)
    const u16* __restrict__ Whhb,      // (6144 x 1536) bf16, rows interleaved
    const float* __restrict__ XW_f,    // (256 x 6144) interleaved, biases in
    float* __restrict__ cbuf,          // (256 x 1536) c state (in-place)
    u16* __restrict__ hbf_out,         // (256 x 1536) bf16 h(t)
    float* __restrict__ hs_f) {        // (256 x 1536) fp32 h(t) slice
  __shared__ __align__(16) char lds[24576];   // A dbuf 2x4K + B dbuf 2x8K
  const int tid  = threadIdx.x;
  const int lane = tid & 63;
  const int wid  = tid >> 6;
  const int wr   = wid >> 1;   // 0..1 (m half: 16 rows)
  const int wc   = wid & 1;    // 0..1 (n half: 32 cols)

  // XCD-aware mapping (bijective): xcd = orig&7, jj = orig>>3 in [0,96):
  // n-tile = 12*xcd + jj>>3, m-tile = jj&7.
  const int orig = blockIdx.x;
  const int xcd  = orig & 7;
  const int jj   = orig >> 3;
  const int n0   = (12 * xcd + (jj >> 3)) * 64;   // interleaved col base
  const int m0   = (jj & 7) * 32;                 // batch base
  const int K    = HID;

  const int fr    = lane & 15;
  const int kb    = (lane >> 4) << 4;
  const int swz   = (fr & 7) << 4;
  const int colp0 = kb ^ swz;
  const int colp1 = (64 | kb) ^ swz;

  // staging: thread t -> row = t>>3 (0..31), cb = (t&7)*16 ^ swz(row)
  const int srow = tid >> 3;
  const int scb  = ((tid & 7) << 4) ^ ((srow & 7) << 4);
  const u16* gA = hbf_in + (size_t)(m0 + srow) * K + (scb >> 1);
  const u16* gB = Whhb   + (size_t)(n0 + srow) * K + (scb >> 1);
  const int wdst = wid << 10;

  char* ldsA = lds;            // [2][4096]  (32 rows x 128B)
  char* ldsB = lds + 8192;     // [2][8192]  (64 rows x 128B)
  char* aRowB = ldsA + (wr * 16 + fr) * 128;
  char* bRowB = ldsB + (wc * 32 + fr) * 128;

  f32x4 acc[2] = {};   // 16 x (2x16) per wave
  const int NT = K >> 6;   // 24

  GLL(gA,                  ldsA + wdst);
  GLL(gB,                  ldsB + wdst);
  GLL(gB + (size_t)32 * K, ldsB + 4096 + wdst);

  for (int t = 0; t < NT; ++t) {
    const int p = t & 1;
    char* aRow = aRowB + p * 4096;
    char* bRow = bRowB + p * 8192;
    char* An = ldsA + (p ^ 1) * 4096;
    char* Bn = ldsB + (p ^ 1) * 8192;
    const u16* gAn = gA + (size_t)(t + 1) * 64;
    const u16* gBn = gB + (size_t)(t + 1) * 64;

    if (t + 1 < NT) {
      GLL(gAn,                  An + wdst);
      GLL(gBn,                  Bn + wdst);
      GLL(gBn + (size_t)32 * K, Bn + 4096 + wdst);
      asm volatile("s_waitcnt vmcnt(3)" ::: "memory");
    } else {
      asm volatile("s_waitcnt vmcnt(0)" ::: "memory");
    }
    SBAR();

    bf16x8 a[2], b[2][2];
    a[0] = *(const bf16x8*)(aRow + colp0);
    a[1] = *(const bf16x8*)(aRow + colp1);
#pragma unroll
    for (int j = 0; j < 2; ++j) {
      b[0][j] = *(const bf16x8*)(bRow + j * 2048 + colp0);
      b[1][j] = *(const bf16x8*)(bRow + j * 2048 + colp1);
    }
    WAIT_LGKM0();
    __builtin_amdgcn_s_setprio(1);
#pragma unroll
    for (int k = 0; k < 2; ++k)
#pragma unroll
      for (int j = 0; j < 2; ++j)
        acc[j] = __builtin_amdgcn_mfma_f32_16x16x32_bf16(a[k], b[k][j], acc[j], 0, 0, 0);
    __builtin_amdgcn_s_setprio(0);
    SBAR();
  }

  // ---- epilogue: acc -> LDS (stride 68 floats kills bank conflicts) ----
  float* sacc = (float*)lds;   // [32][68] = 8704 B, gemm bufs dead
  const int r0 = (lane >> 4) << 2;
  const int cc = lane & 15;
#pragma unroll
  for (int j = 0; j < 2; ++j) {
    const int ml = wr * 16 + r0;
    const int nl = wc * 32 + j * 16 + cc;
#pragma unroll
    for (int r = 0; r < 4; ++r)
      sacc[(ml + r) * 68 + nl] = acc[j][r];
  }
  __syncthreads();

  // ---- cell: 32 batch x 16 j's; gates i,f,g,o = interleaved cols 4j+0..3
  for (int it = tid; it < 512; it += 256) {
    const int bl = it >> 4;                 // local batch 0..31
    const int jl = it & 15;                 // local j 0..15
    const int b  = m0 + bl;
    const int jg = (n0 >> 2) + jl;          // global j
    const float4 hw = *(const float4*)&sacc[bl * 68 + jl * 4];
    const float4 xw = *(const float4*)&XW_f[(size_t)b * GATES + n0 + jl * 4];
    const float gi = xw.x + hw.x;
    const float gf = xw.y + hw.y;
    const float gg = xw.z + hw.z;
    const float go = xw.w + hw.w;
    const int cidx = b * HID + jg;
    const float cp = cbuf[cidx];
    const float cv = sigm(gf) * cp + sigm(gi) * tanhf(gg);
    const float h  = tanhf(sigm(go) * tanhf(cv));
    cbuf[cidx]    = cv;
    hbf_out[cidx] = f2bf(h);
    hs_f[cidx]    = h;
  }
}

// ---------------- first step: gates = XW' only (biases included) ----------------
__global__ void cell_first(const float* __restrict__ XW,
                           float* __restrict__ cbuf,
                           u16* __restrict__ hbf_out,
                           float* __restrict__ hs_f) {
  int it = blockIdx.x * blockDim.x + threadIdx.x;   // 256*1536 items
  int b = it / HID;
  int j = it - b * HID;
  const float4 xw = *(const float4*)&XW[(size_t)b * GATES + 4 * j];
  const float cv = sigm(xw.x) * tanhf(xw.z);
  const float h  = tanhf(sigm(xw.w) * tanhf(cv));
  cbuf[it]    = cv;
  hbf_out[it] = f2bf(h);
  hs_f[it]    = h;
}

// ---------------- final: out[b,n,o] = relu(out2[b,n,:]) @ lin_W^T + lin_b ----------------
__global__ __launch_bounds__(256) void final_k(const float* __restrict__ hs,
                                               const float* __restrict__ lin_W,
                                               const float* __restrict__ lin_b,
                                               float* __restrict__ out) {
  __shared__ float Wsh[12 * 36];
  __shared__ float bsh[12];
  for (int i = threadIdx.x; i < 12 * 36; i += blockDim.x) Wsh[i] = lin_W[i];
  if (threadIdx.x < 12) bsh[threadIdx.x] = lin_b[threadIdx.x];
  __syncthreads();

  int idx = blockIdx.x * blockDim.x + threadIdx.x;
  int b = idx >> 9;
  int n = idx & 511;

  float acc[12];
#pragma unroll
  for (int o = 0; o < 12; ++o) acc[o] = bsh[o];

#pragma unroll
  for (int kk = 0; kk < 3; ++kk)
#pragma unroll
    for (int f = 0; f < 12; ++f) {
      float v = hs[(size_t)(f * BSZ + b) * HID + 3 * n + kk];
      v = fmaxf(v, 0.0f);
      int j = 12 * kk + f;
#pragma unroll
      for (int o = 0; o < 12; ++o) acc[o] += v * Wsh[o * 36 + j];
    }

#pragma unroll
  for (int o = 0; o < 12; ++o) out[(size_t)idx * 12 + o] = acc[o];
}

extern "C" void kernel_launch(void* const* d_in, const int* in_sizes, int n_in,
                              void* d_out, int out_size, void* d_ws, size_t ws_size,
                              hipStream_t stream) {
  (void)in_sizes; (void)n_in; (void)out_size; (void)ws_size;
  const float* X     = (const float*)d_in[1];
  const float* W_ih  = (const float*)d_in[2];
  const float* W_hh  = (const float*)d_in[3];
  const float* b_ih  = (const float*)d_in[4];
  const float* b_hh  = (const float*)d_in[5];
  const float* lin_W = (const float*)d_in[6];
  const float* lin_b = (const float*)d_in[7];
  float* out = (float*)d_out;

  char* p = (char*)d_ws;
  u16*   Ax   = (u16*)p;   p += (size_t)MROWS * INSZ * 2;
  u16*   Wihb = (u16*)p;   p += (size_t)GATES * INSZ * 2;
  u16*   Whhb = (u16*)p;   p += (size_t)GATES * HID * 2;
  float* XW   = (float*)p; p += (size_t)MROWS * GATES * 4;
  u16*   hbfA = (u16*)p;   p += (size_t)BSZ * HID * 2;
  u16*   hbfB = (u16*)p;   p += (size_t)BSZ * HID * 2;
  float* cbuf = (float*)p; p += (size_t)BSZ * HID * 4;
  float* hs   = (float*)p; p += (size_t)FF * BSZ * HID * 4;

  hipFuncSetAttribute((const void*)gemm8p,
                      hipFuncAttributeMaxDynamicSharedMemorySize, LDS_TOTAL);

  // 1) convert weights (gate-interleaved rows) + pack X
  cvt_perm<<<(GATES * (INSZ / 4)) / 256, 256, 0, stream>>>(W_ih, Wihb, INSZ / 4);
  cvt_perm<<<(GATES * (HID / 4)) / 256, 256, 0, stream>>>(W_hh, Whhb, HID / 4);
  pack_x4<<<(BSZ * INSZ / 4) / 256, 256, 0, stream>>>(X, Ax);

  // 2) hoisted input GEMM: XW (interleaved cols) = Ax @ Wihb^T + biases
  gemm8p<<<256, 512, LDS_TOTAL, stream>>>(Ax, Wihb, b_ih, b_hh, XW,
                                          MROWS, GATES, INSZ);

  // 3) recurrence: fused GEMM+cell per step, hbf double-buffered
  u16* bufs[2] = { hbfA, hbfB };
  cell_first<<<(BSZ * HID) / 256, 256, 0, stream>>>(XW, cbuf, bufs[0], hs);
  for (int f = 1; f < FF; ++f) {
    gemm_cell<<<768, 256, 0, stream>>>(
        bufs[(f - 1) & 1], Whhb, XW + (size_t)f * BSZ * GATES, cbuf,
        bufs[f & 1], hs + (size_t)f * BSZ * HID);
  }

  // 4) final linear
  final_k<<<(BSZ * NN) / 256, 256, 0, stream>>>(hs, lin_W, lin_b, out);
}

// Round 19
// 419.452 us; speedup vs baseline: 1.0195x; 1.0195x over previous
//
#include <hip/hip_runtime.h>
#include <hip/hip_bf16.h>
#include <stdint.h>

typedef uint16_t u16;
typedef __attribute__((ext_vector_type(8))) __bf16 bf16x8;
typedef __attribute__((ext_vector_type(4))) float f32x4;
typedef __attribute__((ext_vector_type(4))) u16 u16x4;

// Problem constants
#define BSZ   256
#define NN    512
#define TT    12
#define FF    12
#define HID   1536
#define INSZ  6144    // N*F = LSTM input size
#define GATES 6144    // 4*HID
#define MROWS 3072    // FF*BSZ rows of the hoisted input GEMM

static __device__ __forceinline__ u16 f2bf(float x) {
  uint32_t u = __builtin_bit_cast(uint32_t, x);
  u += 0x7fffu + ((u >> 16) & 1u);   // RNE
  return (u16)(u >> 16);
}

static __device__ __forceinline__ float bf2f(u16 x) {
  return __builtin_bit_cast(float, (uint32_t)x << 16);
}

static __device__ __forceinline__ float sigm(float x) {
  return 1.0f / (1.0f + expf(-x));
}

// ---------------- fp32 -> bf16 convert + gate-interleave row permute ----------------
// out row' = 4*(r%HID) + r/HID  (orig row r = g*HID + j  ->  row' = 4j+g)
__global__ void cvt_perm(const float* __restrict__ in, u16* __restrict__ out,
                         int ncol4) {
  long idx = (long)blockIdx.x * blockDim.x + threadIdx.x;   // r*ncol4 + c4
  int r  = (int)(idx / ncol4);
  int c4 = (int)(idx - (long)r * ncol4);
  int rp = ((r % HID) << 2) + r / HID;
  float4 v = ((const float4*)in)[idx];
  u16x4 w = { f2bf(v.x), f2bf(v.y), f2bf(v.z), f2bf(v.w) };
  ((u16x4*)out)[(size_t)rp * ncol4 + c4] = w;
}

// ---------------- pack X: 4 k's per thread -> coalesced u16x4 writes ----------------
__global__ void pack_x4(const float* __restrict__ X, u16* __restrict__ Ax) {
  int idx = blockIdx.x * blockDim.x + threadIdx.x;   // (b, k4), k4 in [0,1536)
  int b  = idx / (INSZ / 4);
  int k4 = idx - b * (INSZ / 4);
  const float* xp = X + (size_t)b * (INSZ * FF) + (size_t)k4 * (4 * FF);
  float4 v[12];   // 48 floats = [kk 0..3][f 0..11]
#pragma unroll
  for (int j = 0; j < 12; ++j) v[j] = ((const float4*)xp)[j];
  const float* vf = (const float*)v;
#pragma unroll
  for (int f = 0; f < FF; ++f) {
    u16x4 w = { f2bf(vf[0 * FF + f]), f2bf(vf[1 * FF + f]),
                f2bf(vf[2 * FF + f]), f2bf(vf[3 * FF + f]) };
    *(u16x4*)&Ax[(size_t)(f * BSZ + b) * INSZ + k4 * 4] = w;
  }
}

// =====================================================================
// Deep-pipelined bf16 GEMM. R16: cross-tile MFMA deferral — the last
// two quadrant-clusters of tile t (q11k1/q10k1, operands in registers)
// execute during tile t+1's p0/p1 read burst, filling the post-barrier
// LDS-burst bubble. lgkmcnt(0) before the end barrier guarantees all
// buffer-p ds_reads delivered before t+1's GLLs overwrite p.
// Tile 192x384, BK=64, 8 waves (2x4), 2 barriers/K-tile.
// =====================================================================
#define BM8 192
#define BN8 384
#define LDSA_SZ 24576
#define LDSB_SZ 49152
#define LDS_TOTAL (2 * (LDSA_SZ + LDSB_SZ))   // 147456

#define GLL(src, dst)                                                          \
  __builtin_amdgcn_global_load_lds(                                            \
      (const __attribute__((address_space(1))) void*)(src),                    \
      (__attribute__((address_space(3))) void*)(dst), 16, 0, 0)

#define SBAR() asm volatile("s_barrier" ::: "memory")
#define SCHED_FENCE_DS() __builtin_amdgcn_sched_barrier(0x7F)
#define WAIT_LGKM0()                                                           \
  do {                                                                         \
    asm volatile("s_waitcnt lgkmcnt(0)" ::: "memory");                         \
    __builtin_amdgcn_sched_barrier(0);                                         \
  } while (0)

#define MFMA9(AF, BF, RO, CO)                                                  \
  do {                                                                         \
    __builtin_amdgcn_s_setprio(1);                                             \
    _Pragma("unroll") for (int i = 0; i < 3; ++i)                              \
        _Pragma("unroll") for (int j = 0; j < 3; ++j)                          \
            acc[RO + i][CO + j] = __builtin_amdgcn_mfma_f32_16x16x32_bf16(     \
                AF[i], BF[j], acc[RO + i][CO + j], 0, 0, 0);                   \
    __builtin_amdgcn_s_setprio(0);                                             \
  } while (0)

__global__ __launch_bounds__(512, 1) void gemm8p(
    const u16* __restrict__ A, const u16* __restrict__ Bt,
    const float* __restrict__ bi, const float* __restrict__ bh,
    float* __restrict__ C, int M, int N, int K) {
  extern __shared__ __align__(16) char lds[];
  const int tid  = threadIdx.x;
  const int lane = tid & 63;
  const int wid  = tid >> 6;
  const int wr   = wid >> 2;
  const int wc   = wid & 3;

  const int nbx  = N / BN8;
  const int cpx  = gridDim.x >> 3;
  const int orig = blockIdx.x;
  const int wgid = (orig & 7) * cpx + (orig >> 3);
  const int m0   = (wgid / nbx) * BM8;
  const int n0   = (wgid % nbx) * BN8;

  const int fr    = lane & 15;
  const int kb    = (lane >> 4) << 4;
  const int swz   = (fr & 7) << 4;
  const int colp0 = kb ^ swz;
  const int colp1 = (64 | kb) ^ swz;

  const int srow = tid >> 3;
  const int scb  = ((tid & 7) << 4) ^ ((srow & 7) << 4);
  const u16* gA = A  + (size_t)(m0 + srow) * K + (scb >> 1);
  const u16* gB = Bt + (size_t)(n0 + srow) * K + (scb >> 1);
  const int wdst = wid << 10;

  char* ldsA = lds;
  char* ldsB = lds + 2 * LDSA_SZ;
  char* aRowB = ldsA + (wr * 96 + fr) * 128;
  char* bRowB = ldsB + (wc * 96 + fr) * 128;

  f32x4 acc[6][6] = {};
  const int NT = K >> 6;

#pragma unroll
  for (int c = 0; c < 3; ++c) GLL(gA + (size_t)c * 64 * K, ldsA + c * 8192 + wdst);
#pragma unroll
  for (int c = 0; c < 6; ++c) GLL(gB + (size_t)c * 64 * K, ldsB + c * 8192 + wdst);

  bf16x8 a1o[3], b1o[3], b0o[3];   // deferred operands from previous tile

  for (int t = 0; t < NT; ++t) {
    const int p = t & 1;
    char* aRow = aRowB + p * LDSA_SZ;
    char* bRow = bRowB + p * LDSB_SZ;
    char* An = ldsA + (p ^ 1) * LDSA_SZ;
    char* Bn = ldsB + (p ^ 1) * LDSB_SZ;
    const u16* gAn = gA + (size_t)(t + 1) * 64;
    const u16* gBn = gB + (size_t)(t + 1) * 64;
    const bool pf = (t + 1 < NT);

    bf16x8 a0k0[3], b0k0[3], b1k0[3], a1k0[3];
    bf16x8 a0k1[3], b0k1[3], b1k1[3], a1k1[3];

    if (pf) {
#pragma unroll
      for (int c = 0; c < 3; ++c) GLL(gAn + (size_t)c * 64 * K, An + c * 8192 + wdst);
      asm volatile("s_waitcnt vmcnt(3)" ::: "memory");
    } else {
      asm volatile("s_waitcnt vmcnt(0)" ::: "memory");
    }
    SBAR();

    // ---- p0: R a0k0 + b0k0 ; deferred q11(old)
#pragma unroll
    for (int i = 0; i < 3; ++i) {
      a0k0[i] = *(const bf16x8*)(aRow + i * 2048 + colp0);
      b0k0[i] = *(const bf16x8*)(bRow + i * 2048 + colp0);
    }
    if (t > 0) MFMA9(a1o, b1o, 3, 3);
    SCHED_FENCE_DS();

    // ---- p1: R b1k0 ; deferred q10(old) ; GLL B01
#pragma unroll
    for (int i = 0; i < 3; ++i) b1k0[i] = *(const bf16x8*)(bRow + (3 + i) * 2048 + colp0);
    if (t > 0) MFMA9(a1o, b0o, 3, 0);
    if (pf) {
      GLL(gBn + (size_t)0 * 64 * K, Bn + 0 * 8192 + wdst);
      GLL(gBn + (size_t)1 * 64 * K, Bn + 1 * 8192 + wdst);
    }
    SCHED_FENCE_DS();

    // ---- p2: R a1k0 ; q00k0 ; GLL B23
#pragma unroll
    for (int i = 0; i < 3; ++i) a1k0[i] = *(const bf16x8*)(aRow + (3 + i) * 2048 + colp0);
    MFMA9(a0k0, b0k0, 0, 0);
    if (pf) {
      GLL(gBn + (size_t)2 * 64 * K, Bn + 2 * 8192 + wdst);
      GLL(gBn + (size_t)3 * 64 * K, Bn + 3 * 8192 + wdst);
    }
    SCHED_FENCE_DS();

    // ---- p3: R a0k1 ; q01k0 ; GLL B45
#pragma unroll
    for (int i = 0; i < 3; ++i) a0k1[i] = *(const bf16x8*)(aRow + i * 2048 + colp1);
    MFMA9(a0k0, b1k0, 0, 3);
    if (pf) {
      GLL(gBn + (size_t)4 * 64 * K, Bn + 4 * 8192 + wdst);
      GLL(gBn + (size_t)5 * 64 * K, Bn + 5 * 8192 + wdst);
    }
    SCHED_FENCE_DS();

    // ---- p4: R b0k1 ; q11k0
#pragma unroll
    for (int i = 0; i < 3; ++i) b0k1[i] = *(const bf16x8*)(bRow + i * 2048 + colp1);
    MFMA9(a1k0, b1k0, 3, 3);
    SCHED_FENCE_DS();

    // ---- p5: R b1k1 ; q10k0
#pragma unroll
    for (int i = 0; i < 3; ++i) b1k1[i] = *(const bf16x8*)(bRow + (3 + i) * 2048 + colp1);
    MFMA9(a1k0, b0k0, 3, 0);
    SCHED_FENCE_DS();

    // ---- p6: R a1k1 ; q00k1
#pragma unroll
    for (int i = 0; i < 3; ++i) a1k1[i] = *(const bf16x8*)(aRow + (3 + i) * 2048 + colp1);
    MFMA9(a0k1, b0k1, 0, 0);
    SCHED_FENCE_DS();

    // ---- p7: q01k1 ; save deferred operands (q11k1/q10k1 run next iter)
    MFMA9(a0k1, b1k1, 0, 3);
#pragma unroll
    for (int i = 0; i < 3; ++i) { a1o[i] = a1k1[i]; b1o[i] = b1k1[i]; b0o[i] = b0k1[i]; }

    // drain this wave's ds_reads of buffer p before any wave overwrites p
    asm volatile("s_waitcnt lgkmcnt(0)" ::: "memory");
    SBAR();
  }

  // drain deferred clusters of the final tile
  MFMA9(a1o, b1o, 3, 3);
  MFMA9(a1o, b0o, 3, 0);

  const int r0 = (lane >> 4) << 2;
  const int cc = lane & 15;
#pragma unroll
  for (int j = 0; j < 6; ++j) {
    const int col = n0 + wc * 96 + j * 16 + cc;          // interleaved position
    const int oc  = (col & 3) * HID + (col >> 2);        // original gate index
    const float bv = bi[oc] + bh[oc];
#pragma unroll
    for (int i = 0; i < 6; ++i) {
      const size_t rbase = (size_t)(m0 + wr * 96 + i * 16 + r0) * N + col;
#pragma unroll
      for (int r = 0; r < 4; ++r)
        C[rbase + (size_t)r * N] = acc[i][j][r] + bv;
    }
  }
}

// =====================================================================
// Fused step (R15 structure; R16: h ring lives in bf16 hs slices —
// reads hs[f-1], writes hs[f]; separate hbf buffers eliminated).
// 32x64 tile, 768 blocks, BK=64, dbuf 24KB, vmcnt(3), XCD mapping.
// =====================================================================
__global__ __launch_bounds__(256, 4) void gemm_cell(
    const u16* __restrict__ hs_in,     // (256 x 1536) bf16 h(t-1) = hs[f-1]
    const u16* __restrict__ Whhb,      // (6144 x 1536) bf16, rows interleaved
    const float* __restrict__ XW_f,    // (256 x 6144) interleaved, biases in
    float* __restrict__ cbuf,          // (256 x 1536) c state (in-place)
    u16* __restrict__ hs_out) {        // (256 x 1536) bf16 h(t) = hs[f]
  __shared__ __align__(16) char lds[24576];   // A dbuf 2x4K + B dbuf 2x8K
  const int tid  = threadIdx.x;
  const int lane = tid & 63;
  const int wid  = tid >> 6;
  const int wr   = wid >> 1;   // 0..1 (m half: 16 rows)
  const int wc   = wid & 1;    // 0..1 (n half: 32 cols)

  // XCD-aware mapping (bijective): xcd = orig&7, jj = orig>>3 in [0,96):
  // n-tile = 12*xcd + jj>>3, m-tile = jj&7.
  const int orig = blockIdx.x;
  const int xcd  = orig & 7;
  const int jj   = orig >> 3;
  const int n0   = (12 * xcd + (jj >> 3)) * 64;   // interleaved col base
  const int m0   = (jj & 7) * 32;                 // batch base
  const int K    = HID;

  const int fr    = lane & 15;
  const int kb    = (lane >> 4) << 4;
  const int swz   = (fr & 7) << 4;
  const int colp0 = kb ^ swz;
  const int colp1 = (64 | kb) ^ swz;

  const int srow = tid >> 3;
  const int scb  = ((tid & 7) << 4) ^ ((srow & 7) << 4);
  const u16* gA = hs_in + (size_t)(m0 + srow) * K + (scb >> 1);
  const u16* gB = Whhb  + (size_t)(n0 + srow) * K + (scb >> 1);
  const int wdst = wid << 10;

  char* ldsA = lds;            // [2][4096]  (32 rows x 128B)
  char* ldsB = lds + 8192;     // [2][8192]  (64 rows x 128B)
  char* aRowB = ldsA + (wr * 16 + fr) * 128;
  char* bRowB = ldsB + (wc * 32 + fr) * 128;

  f32x4 acc[2] = {};
  const int NT = K >> 6;   // 24

  GLL(gA,                  ldsA + wdst);
  GLL(gB,                  ldsB + wdst);
  GLL(gB + (size_t)32 * K, ldsB + 4096 + wdst);

  for (int t = 0; t < NT; ++t) {
    const int p = t & 1;
    char* aRow = aRowB + p * 4096;
    char* bRow = bRowB + p * 8192;
    char* An = ldsA + (p ^ 1) * 4096;
    char* Bn = ldsB + (p ^ 1) * 8192;
    const u16* gAn = gA + (size_t)(t + 1) * 64;
    const u16* gBn = gB + (size_t)(t + 1) * 64;

    if (t + 1 < NT) {
      GLL(gAn,                  An + wdst);
      GLL(gBn,                  Bn + wdst);
      GLL(gBn + (size_t)32 * K, Bn + 4096 + wdst);
      asm volatile("s_waitcnt vmcnt(3)" ::: "memory");
    } else {
      asm volatile("s_waitcnt vmcnt(0)" ::: "memory");
    }
    SBAR();

    bf16x8 a[2], b[2][2];
    a[0] = *(const bf16x8*)(aRow + colp0);
    a[1] = *(const bf16x8*)(aRow + colp1);
#pragma unroll
    for (int j = 0; j < 2; ++j) {
      b[0][j] = *(const bf16x8*)(bRow + j * 2048 + colp0);
      b[1][j] = *(const bf16x8*)(bRow + j * 2048 + colp1);
    }
    WAIT_LGKM0();
    __builtin_amdgcn_s_setprio(1);
#pragma unroll
    for (int k = 0; k < 2; ++k)
#pragma unroll
      for (int j = 0; j < 2; ++j)
        acc[j] = __builtin_amdgcn_mfma_f32_16x16x32_bf16(a[k], b[k][j], acc[j], 0, 0, 0);
    __builtin_amdgcn_s_setprio(0);
    SBAR();
  }

  // ---- epilogue: acc -> LDS (stride 68 floats kills bank conflicts) ----
  float* sacc = (float*)lds;   // [32][68] = 8704 B, gemm bufs dead
  const int r0 = (lane >> 4) << 2;
  const int cc = lane & 15;
#pragma unroll
  for (int j = 0; j < 2; ++j) {
    const int ml = wr * 16 + r0;
    const int nl = wc * 32 + j * 16 + cc;
#pragma unroll
    for (int r = 0; r < 4; ++r)
      sacc[(ml + r) * 68 + nl] = acc[j][r];
  }
  __syncthreads();

  // ---- cell: 32 batch x 16 j's; gates i,f,g,o = interleaved cols 4j+0..3
  for (int it = tid; it < 512; it += 256) {
    const int bl = it >> 4;                 // local batch 0..31
    const int jl = it & 15;                 // local j 0..15
    const int b  = m0 + bl;
    const int jg = (n0 >> 2) + jl;          // global j
    const float4 hw = *(const float4*)&sacc[bl * 68 + jl * 4];
    const float4 xw = *(const float4*)&XW_f[(size_t)b * GATES + n0 + jl * 4];
    const float gi = xw.x + hw.x;
    const float gf = xw.y + hw.y;
    const float gg = xw.z + hw.z;
    const float go = xw.w + hw.w;
    const int cidx = b * HID + jg;
    const float cp = cbuf[cidx];
    const float cv = sigm(gf) * cp + sigm(gi) * tanhf(gg);
    const float h  = tanhf(sigm(go) * tanhf(cv));
    cbuf[cidx]   = cv;
    hs_out[cidx] = f2bf(h);
  }
}

// ---------------- first step: gates = XW' only (biases included) ----------------
__global__ void cell_first(const float* __restrict__ XW,
                           float* __restrict__ cbuf,
                           u16* __restrict__ hs_out) {
  int it = blockIdx.x * blockDim.x + threadIdx.x;   // 256*1536 items
  int b = it / HID;
  int j = it - b * HID;
  const float4 xw = *(const float4*)&XW[(size_t)b * GATES + 4 * j];
  const float cv = sigm(xw.x) * tanhf(xw.z);
  const float h  = tanhf(sigm(xw.w) * tanhf(cv));
  cbuf[it]   = cv;
  hs_out[it] = f2bf(h);
}

// ---------------- final: out[b,n,o] = relu(out2[b,n,:]) @ lin_W^T + lin_b ----------------
__global__ __launch_bounds__(256) void final_k(const u16* __restrict__ hs,
                                               const float* __restrict__ lin_W,
                                               const float* __restrict__ lin_b,
                                               float* __restrict__ out) {
  __shared__ float Wsh[12 * 36];
  __shared__ float bsh[12];
  for (int i = threadIdx.x; i < 12 * 36; i += blockDim.x) Wsh[i] = lin_W[i];
  if (threadIdx.x < 12) bsh[threadIdx.x] = lin_b[threadIdx.x];
  __syncthreads();

  int idx = blockIdx.x * blockDim.x + threadIdx.x;
  int b = idx >> 9;
  int n = idx & 511;

  float acc[12];
#pragma unroll
  for (int o = 0; o < 12; ++o) acc[o] = bsh[o];

#pragma unroll
  for (int kk = 0; kk < 3; ++kk)
#pragma unroll
    for (int f = 0; f < 12; ++f) {
      float v = bf2f(hs[(size_t)(f * BSZ + b) * HID + 3 * n + kk]);
      v = fmaxf(v, 0.0f);
      int j = 12 * kk + f;
#pragma unroll
      for (int o = 0; o < 12; ++o) acc[o] += v * Wsh[o * 36 + j];
    }

#pragma unroll
  for (int o = 0; o < 12; ++o) out[(size_t)idx * 12 + o] = acc[o];
}

extern "C" void kernel_launch(void* const* d_in, const int* in_sizes, int n_in,
                              void* d_out, int out_size, void* d_ws, size_t ws_size,
                              hipStream_t stream) {
  (void)in_sizes; (void)n_in; (void)out_size; (void)ws_size;
  const float* X     = (const float*)d_in[1];
  const float* W_ih  = (const float*)d_in[2];
  const float* W_hh  = (const float*)d_in[3];
  const float* b_ih  = (const float*)d_in[4];
  const float* b_hh  = (const float*)d_in[5];
  const float* lin_W = (const float*)d_in[6];
  const float* lin_b = (const float*)d_in[7];
  float* out = (float*)d_out;

  char* p = (char*)d_ws;
  u16*   Ax   = (u16*)p;   p += (size_t)MROWS * INSZ * 2;
  u16*   Wihb = (u16*)p;   p += (size_t)GATES * INSZ * 2;
  u16*   Whhb = (u16*)p;   p += (size_t)GATES * HID * 2;
  float* XW   = (float*)p; p += (size_t)MROWS * GATES * 4;
  float* cbuf = (float*)p; p += (size_t)BSZ * HID * 4;
  u16*   hs   = (u16*)p;   p += (size_t)FF * BSZ * HID * 2;   // bf16 h ring + output

  hipFuncSetAttribute((const void*)gemm8p,
                      hipFuncAttributeMaxDynamicSharedMemorySize, LDS_TOTAL);

  // 1) convert weights (gate-interleaved rows) + pack X
  cvt_perm<<<(GATES * (INSZ / 4)) / 256, 256, 0, stream>>>(W_ih, Wihb, INSZ / 4);
  cvt_perm<<<(GATES * (HID / 4)) / 256, 256, 0, stream>>>(W_hh, Whhb, HID / 4);
  pack_x4<<<(BSZ * INSZ / 4) / 256, 256, 0, stream>>>(X, Ax);

  // 2) hoisted input GEMM: XW (interleaved cols) = Ax @ Wihb^T + biases
  gemm8p<<<256, 512, LDS_TOTAL, stream>>>(Ax, Wihb, b_ih, b_hh, XW,
                                          MROWS, GATES, INSZ);

  // 3) recurrence: fused GEMM+cell per step; h ring = bf16 hs slices
  const size_t S = (size_t)BSZ * HID;
  cell_first<<<(BSZ * HID) / 256, 256, 0, stream>>>(XW, cbuf, hs);
  for (int f = 1; f < FF; ++f) {
    gemm_cell<<<768, 256, 0, stream>>>(
        hs + (f - 1) * S, Whhb, XW + (size_t)f * BSZ * GATES, cbuf, hs + f * S);
  }

  // 4) final linear
  final_k<<<(BSZ * NN) / 256, 256, 0, stream>>>(hs, lin_W, lin_b, out);
}

// Round 20
// 417.166 us; speedup vs baseline: 1.0251x; 1.0055x over previous
//
#include <hip/hip_runtime.h>
#include <hip/hip_bf16.h>
#include <stdint.h>

typedef uint16_t u16;
typedef __attribute__((ext_vector_type(8))) __bf16 bf16x8;
typedef __attribute__((ext_vector_type(4))) float f32x4;
typedef __attribute__((ext_vector_type(4))) u16 u16x4;

// Problem constants
#define BSZ   256
#define NN    512
#define TT    12
#define FF    12
#define HID   1536
#define INSZ  6144    // N*F = LSTM input size
#define GATES 6144    // 4*HID
#define MROWS 3072    // FF*BSZ rows of the hoisted input GEMM

static __device__ __forceinline__ u16 f2bf(float x) {
  uint32_t u = __builtin_bit_cast(uint32_t, x);
  u += 0x7fffu + ((u >> 16) & 1u);   // RNE
  return (u16)(u >> 16);
}

static __device__ __forceinline__ float bf2f(u16 x) {
  return __builtin_bit_cast(float, (uint32_t)x << 16);
}

static __device__ __forceinline__ float sigm(float x) {
  return 1.0f / (1.0f + expf(-x));
}

// ---------------- fp32 -> bf16 convert + gate-interleave row permute ----------------
// out row' = 4*(r%HID) + r/HID  (orig row r = g*HID + j  ->  row' = 4j+g)
__global__ void cvt_perm(const float* __restrict__ in, u16* __restrict__ out,
                         int ncol4) {
  long idx = (long)blockIdx.x * blockDim.x + threadIdx.x;   // r*ncol4 + c4
  int r  = (int)(idx / ncol4);
  int c4 = (int)(idx - (long)r * ncol4);
  int rp = ((r % HID) << 2) + r / HID;
  float4 v = ((const float4*)in)[idx];
  u16x4 w = { f2bf(v.x), f2bf(v.y), f2bf(v.z), f2bf(v.w) };
  ((u16x4*)out)[(size_t)rp * ncol4 + c4] = w;
}

// ---------------- pack X: 4 k's per thread -> coalesced u16x4 writes ----------------
__global__ void pack_x4(const float* __restrict__ X, u16* __restrict__ Ax) {
  int idx = blockIdx.x * blockDim.x + threadIdx.x;   // (b, k4), k4 in [0,1536)
  int b  = idx / (INSZ / 4);
  int k4 = idx - b * (INSZ / 4);
  const float* xp = X + (size_t)b * (INSZ * FF) + (size_t)k4 * (4 * FF);
  float4 v[12];   // 48 floats = [kk 0..3][f 0..11]
#pragma unroll
  for (int j = 0; j < 12; ++j) v[j] = ((const float4*)xp)[j];
  const float* vf = (const float*)v;
#pragma unroll
  for (int f = 0; f < FF; ++f) {
    u16x4 w = { f2bf(vf[0 * FF + f]), f2bf(vf[1 * FF + f]),
                f2bf(vf[2 * FF + f]), f2bf(vf[3 * FF + f]) };
    *(u16x4*)&Ax[(size_t)(f * BSZ + b) * INSZ + k4 * 4] = w;
  }
}

// =====================================================================
// Deep-pipelined bf16 GEMM (R16 structure: cross-tile MFMA deferral,
// 2 barriers/K-tile). R20: C output stored as bf16 (halves WRITE traffic;
// gates tolerate bf16 rounding). Tile 192x384, BK=64, 8 waves (2x4).
// =====================================================================
#define BM8 192
#define BN8 384
#define LDSA_SZ 24576
#define LDSB_SZ 49152
#define LDS_TOTAL (2 * (LDSA_SZ + LDSB_SZ))   // 147456

#define GLL(src, dst)                                                          \
  __builtin_amdgcn_global_load_lds(                                            \
      (const __attribute__((address_space(1))) void*)(src),                    \
      (__attribute__((address_space(3))) void*)(dst), 16, 0, 0)

#define SBAR() asm volatile("s_barrier" ::: "memory")
#define SCHED_FENCE_DS() __builtin_amdgcn_sched_barrier(0x7F)
#define WAIT_LGKM0()                                                           \
  do {                                                                         \
    asm volatile("s_waitcnt lgkmcnt(0)" ::: "memory");                         \
    __builtin_amdgcn_sched_barrier(0);                                         \
  } while (0)

#define MFMA9(AF, BF, RO, CO)                                                  \
  do {                                                                         \
    __builtin_amdgcn_s_setprio(1);                                             \
    _Pragma("unroll") for (int i = 0; i < 3; ++i)                              \
        _Pragma("unroll") for (int j = 0; j < 3; ++j)                          \
            acc[RO + i][CO + j] = __builtin_amdgcn_mfma_f32_16x16x32_bf16(     \
                AF[i], BF[j], acc[RO + i][CO + j], 0, 0, 0);                   \
    __builtin_amdgcn_s_setprio(0);                                             \
  } while (0)

__global__ __launch_bounds__(512, 1) void gemm8p(
    const u16* __restrict__ A, const u16* __restrict__ Bt,
    const float* __restrict__ bi, const float* __restrict__ bh,
    u16* __restrict__ C, int M, int N, int K) {
  extern __shared__ __align__(16) char lds[];
  const int tid  = threadIdx.x;
  const int lane = tid & 63;
  const int wid  = tid >> 6;
  const int wr   = wid >> 2;
  const int wc   = wid & 3;

  const int nbx  = N / BN8;
  const int cpx  = gridDim.x >> 3;
  const int orig = blockIdx.x;
  const int wgid = (orig & 7) * cpx + (orig >> 3);
  const int m0   = (wgid / nbx) * BM8;
  const int n0   = (wgid % nbx) * BN8;

  const int fr    = lane & 15;
  const int kb    = (lane >> 4) << 4;
  const int swz   = (fr & 7) << 4;
  const int colp0 = kb ^ swz;
  const int colp1 = (64 | kb) ^ swz;

  const int srow = tid >> 3;
  const int scb  = ((tid & 7) << 4) ^ ((srow & 7) << 4);
  const u16* gA = A  + (size_t)(m0 + srow) * K + (scb >> 1);
  const u16* gB = Bt + (size_t)(n0 + srow) * K + (scb >> 1);
  const int wdst = wid << 10;

  char* ldsA = lds;
  char* ldsB = lds + 2 * LDSA_SZ;
  char* aRowB = ldsA + (wr * 96 + fr) * 128;
  char* bRowB = ldsB + (wc * 96 + fr) * 128;

  f32x4 acc[6][6] = {};
  const int NT = K >> 6;

#pragma unroll
  for (int c = 0; c < 3; ++c) GLL(gA + (size_t)c * 64 * K, ldsA + c * 8192 + wdst);
#pragma unroll
  for (int c = 0; c < 6; ++c) GLL(gB + (size_t)c * 64 * K, ldsB + c * 8192 + wdst);

  bf16x8 a1o[3], b1o[3], b0o[3];   // deferred operands from previous tile

  for (int t = 0; t < NT; ++t) {
    const int p = t & 1;
    char* aRow = aRowB + p * LDSA_SZ;
    char* bRow = bRowB + p * LDSB_SZ;
    char* An = ldsA + (p ^ 1) * LDSA_SZ;
    char* Bn = ldsB + (p ^ 1) * LDSB_SZ;
    const u16* gAn = gA + (size_t)(t + 1) * 64;
    const u16* gBn = gB + (size_t)(t + 1) * 64;
    const bool pf = (t + 1 < NT);

    bf16x8 a0k0[3], b0k0[3], b1k0[3], a1k0[3];
    bf16x8 a0k1[3], b0k1[3], b1k1[3], a1k1[3];

    if (pf) {
#pragma unroll
      for (int c = 0; c < 3; ++c) GLL(gAn + (size_t)c * 64 * K, An + c * 8192 + wdst);
      asm volatile("s_waitcnt vmcnt(3)" ::: "memory");
    } else {
      asm volatile("s_waitcnt vmcnt(0)" ::: "memory");
    }
    SBAR();

    // ---- p0: R a0k0 + b0k0 ; deferred q11(old)
#pragma unroll
    for (int i = 0; i < 3; ++i) {
      a0k0[i] = *(const bf16x8*)(aRow + i * 2048 + colp0);
      b0k0[i] = *(const bf16x8*)(bRow + i * 2048 + colp0);
    }
    if (t > 0) MFMA9(a1o, b1o, 3, 3);
    SCHED_FENCE_DS();

    // ---- p1: R b1k0 ; deferred q10(old) ; GLL B01
#pragma unroll
    for (int i = 0; i < 3; ++i) b1k0[i] = *(const bf16x8*)(bRow + (3 + i) * 2048 + colp0);
    if (t > 0) MFMA9(a1o, b0o, 3, 0);
    if (pf) {
      GLL(gBn + (size_t)0 * 64 * K, Bn + 0 * 8192 + wdst);
      GLL(gBn + (size_t)1 * 64 * K, Bn + 1 * 8192 + wdst);
    }
    SCHED_FENCE_DS();

    // ---- p2: R a1k0 ; q00k0 ; GLL B23
#pragma unroll
    for (int i = 0; i < 3; ++i) a1k0[i] = *(const bf16x8*)(aRow + (3 + i) * 2048 + colp0);
    MFMA9(a0k0, b0k0, 0, 0);
    if (pf) {
      GLL(gBn + (size_t)2 * 64 * K, Bn + 2 * 8192 + wdst);
      GLL(gBn + (size_t)3 * 64 * K, Bn + 3 * 8192 + wdst);
    }
    SCHED_FENCE_DS();

    // ---- p3: R a0k1 ; q01k0 ; GLL B45
#pragma unroll
    for (int i = 0; i < 3; ++i) a0k1[i] = *(const bf16x8*)(aRow + i * 2048 + colp1);
    MFMA9(a0k0, b1k0, 0, 3);
    if (pf) {
      GLL(gBn + (size_t)4 * 64 * K, Bn + 4 * 8192 + wdst);
      GLL(gBn + (size_t)5 * 64 * K, Bn + 5 * 8192 + wdst);
    }
    SCHED_FENCE_DS();

    // ---- p4: R b0k1 ; q11k0
#pragma unroll
    for (int i = 0; i < 3; ++i) b0k1[i] = *(const bf16x8*)(bRow + i * 2048 + colp1);
    MFMA9(a1k0, b1k0, 3, 3);
    SCHED_FENCE_DS();

    // ---- p5: R b1k1 ; q10k0
#pragma unroll
    for (int i = 0; i < 3; ++i) b1k1[i] = *(const bf16x8*)(bRow + (3 + i) * 2048 + colp1);
    MFMA9(a1k0, b0k0, 3, 0);
    SCHED_FENCE_DS();

    // ---- p6: R a1k1 ; q00k1
#pragma unroll
    for (int i = 0; i < 3; ++i) a1k1[i] = *(const bf16x8*)(aRow + (3 + i) * 2048 + colp1);
    MFMA9(a0k1, b0k1, 0, 0);
    SCHED_FENCE_DS();

    // ---- p7: q01k1 ; save deferred operands (q11k1/q10k1 run next iter)
    MFMA9(a0k1, b1k1, 0, 3);
#pragma unroll
    for (int i = 0; i < 3; ++i) { a1o[i] = a1k1[i]; b1o[i] = b1k1[i]; b0o[i] = b0k1[i]; }

    // drain this wave's ds_reads of buffer p before any wave overwrites p
    asm volatile("s_waitcnt lgkmcnt(0)" ::: "memory");
    SBAR();
  }

  // drain deferred clusters of the final tile
  MFMA9(a1o, b1o, 3, 3);
  MFMA9(a1o, b0o, 3, 0);

  const int r0 = (lane >> 4) << 2;
  const int cc = lane & 15;
#pragma unroll
  for (int j = 0; j < 6; ++j) {
    const int col = n0 + wc * 96 + j * 16 + cc;          // interleaved position
    const int oc  = (col & 3) * HID + (col >> 2);        // original gate index
    const float bv = bi[oc] + bh[oc];
#pragma unroll
    for (int i = 0; i < 6; ++i) {
      const size_t rbase = (size_t)(m0 + wr * 96 + i * 16 + r0) * N + col;
#pragma unroll
      for (int r = 0; r < 4; ++r)
        C[rbase + (size_t)r * N] = f2bf(acc[i][j][r] + bv);
    }
  }
}

// =====================================================================
// Fused step (R16 structure; R20: XW read as bf16).
// 32x64 tile, 768 blocks, BK=64, dbuf 24KB, vmcnt(3), XCD mapping.
// =====================================================================
__global__ __launch_bounds__(256, 4) void gemm_cell(
    const u16* __restrict__ hs_in,     // (256 x 1536) bf16 h(t-1) = hs[f-1]
    const u16* __restrict__ Whhb,      // (6144 x 1536) bf16, rows interleaved
    const u16* __restrict__ XW_b,      // (256 x 6144) bf16 interleaved, biases in
    float* __restrict__ cbuf,          // (256 x 1536) c state (in-place)
    u16* __restrict__ hs_out) {        // (256 x 1536) bf16 h(t) = hs[f]
  __shared__ __align__(16) char lds[24576];   // A dbuf 2x4K + B dbuf 2x8K
  const int tid  = threadIdx.x;
  const int lane = tid & 63;
  const int wid  = tid >> 6;
  const int wr   = wid >> 1;   // 0..1 (m half: 16 rows)
  const int wc   = wid & 1;    // 0..1 (n half: 32 cols)

  // XCD-aware mapping (bijective): xcd = orig&7, jj = orig>>3 in [0,96):
  // n-tile = 12*xcd + jj>>3, m-tile = jj&7.
  const int orig = blockIdx.x;
  const int xcd  = orig & 7;
  const int jj   = orig >> 3;
  const int n0   = (12 * xcd + (jj >> 3)) * 64;   // interleaved col base
  const int m0   = (jj & 7) * 32;                 // batch base
  const int K    = HID;

  const int fr    = lane & 15;
  const int kb    = (lane >> 4) << 4;
  const int swz   = (fr & 7) << 4;
  const int colp0 = kb ^ swz;
  const int colp1 = (64 | kb) ^ swz;

  const int srow = tid >> 3;
  const int scb  = ((tid & 7) << 4) ^ ((srow & 7) << 4);
  const u16* gA = hs_in + (size_t)(m0 + srow) * K + (scb >> 1);
  const u16* gB = Whhb  + (size_t)(n0 + srow) * K + (scb >> 1);
  const int wdst = wid << 10;

  char* ldsA = lds;            // [2][4096]  (32 rows x 128B)
  char* ldsB = lds + 8192;     // [2][8192]  (64 rows x 128B)
  char* aRowB = ldsA + (wr * 16 + fr) * 128;
  char* bRowB = ldsB + (wc * 32 + fr) * 128;

  f32x4 acc[2] = {};
  const int NT = K >> 6;   // 24

  GLL(gA,                  ldsA + wdst);
  GLL(gB,                  ldsB + wdst);
  GLL(gB + (size_t)32 * K, ldsB + 4096 + wdst);

  for (int t = 0; t < NT; ++t) {
    const int p = t & 1;
    char* aRow = aRowB + p * 4096;
    char* bRow = bRowB + p * 8192;
    char* An = ldsA + (p ^ 1) * 4096;
    char* Bn = ldsB + (p ^ 1) * 8192;
    const u16* gAn = gA + (size_t)(t + 1) * 64;
    const u16* gBn = gB + (size_t)(t + 1) * 64;

    if (t + 1 < NT) {
      GLL(gAn,                  An + wdst);
      GLL(gBn,                  Bn + wdst);
      GLL(gBn + (size_t)32 * K, Bn + 4096 + wdst);
      asm volatile("s_waitcnt vmcnt(3)" ::: "memory");
    } else {
      asm volatile("s_waitcnt vmcnt(0)" ::: "memory");
    }
    SBAR();

    bf16x8 a[2], b[2][2];
    a[0] = *(const bf16x8*)(aRow + colp0);
    a[1] = *(const bf16x8*)(aRow + colp1);
#pragma unroll
    for (int j = 0; j < 2; ++j) {
      b[0][j] = *(const bf16x8*)(bRow + j * 2048 + colp0);
      b[1][j] = *(const bf16x8*)(bRow + j * 2048 + colp1);
    }
    WAIT_LGKM0();
    __builtin_amdgcn_s_setprio(1);
#pragma unroll
    for (int k = 0; k < 2; ++k)
#pragma unroll
      for (int j = 0; j < 2; ++j)
        acc[j] = __builtin_amdgcn_mfma_f32_16x16x32_bf16(a[k], b[k][j], acc[j], 0, 0, 0);
    __builtin_amdgcn_s_setprio(0);
    SBAR();
  }

  // ---- epilogue: acc -> LDS (stride 68 floats kills bank conflicts) ----
  float* sacc = (float*)lds;   // [32][68] = 8704 B, gemm bufs dead
  const int r0 = (lane >> 4) << 2;
  const int cc = lane & 15;
#pragma unroll
  for (int j = 0; j < 2; ++j) {
    const int ml = wr * 16 + r0;
    const int nl = wc * 32 + j * 16 + cc;
#pragma unroll
    for (int r = 0; r < 4; ++r)
      sacc[(ml + r) * 68 + nl] = acc[j][r];
  }
  __syncthreads();

  // ---- cell: 32 batch x 16 j's; gates i,f,g,o = interleaved cols 4j+0..3
  for (int it = tid; it < 512; it += 256) {
    const int bl = it >> 4;                 // local batch 0..31
    const int jl = it & 15;                 // local j 0..15
    const int b  = m0 + bl;
    const int jg = (n0 >> 2) + jl;          // global j
    const float4 hw = *(const float4*)&sacc[bl * 68 + jl * 4];
    const u16x4 xq = *(const u16x4*)&XW_b[(size_t)b * GATES + n0 + jl * 4];
    const float gi = bf2f(xq.x) + hw.x;
    const float gf = bf2f(xq.y) + hw.y;
    const float gg = bf2f(xq.z) + hw.z;
    const float go = bf2f(xq.w) + hw.w;
    const int cidx = b * HID + jg;
    const float cp = cbuf[cidx];
    const float cv = sigm(gf) * cp + sigm(gi) * tanhf(gg);
    const float h  = tanhf(sigm(go) * tanhf(cv));
    cbuf[cidx]   = cv;
    hs_out[cidx] = f2bf(h);
  }
}

// ---------------- first step: gates = XW' only (biases included) ----------------
__global__ void cell_first(const u16* __restrict__ XW,
                           float* __restrict__ cbuf,
                           u16* __restrict__ hs_out) {
  int it = blockIdx.x * blockDim.x + threadIdx.x;   // 256*1536 items
  int b = it / HID;
  int j = it - b * HID;
  const u16x4 xq = *(const u16x4*)&XW[(size_t)b * GATES + 4 * j];
  const float cv = sigm(bf2f(xq.x)) * tanhf(bf2f(xq.z));
  const float h  = tanhf(sigm(bf2f(xq.w)) * tanhf(cv));
  cbuf[it]   = cv;
  hs_out[it] = f2bf(h);
}

// ---------------- final: out[b,n,o] = relu(out2[b,n,:]) @ lin_W^T + lin_b ----------------
__global__ __launch_bounds__(256) void final_k(const u16* __restrict__ hs,
                                               const float* __restrict__ lin_W,
                                               const float* __restrict__ lin_b,
                                               float* __restrict__ out) {
  __shared__ float Wsh[12 * 36];
  __shared__ float bsh[12];
  for (int i = threadIdx.x; i < 12 * 36; i += blockDim.x) Wsh[i] = lin_W[i];
  if (threadIdx.x < 12) bsh[threadIdx.x] = lin_b[threadIdx.x];
  __syncthreads();

  int idx = blockIdx.x * blockDim.x + threadIdx.x;
  int b = idx >> 9;
  int n = idx & 511;

  float acc[12];
#pragma unroll
  for (int o = 0; o < 12; ++o) acc[o] = bsh[o];

#pragma unroll
  for (int kk = 0; kk < 3; ++kk)
#pragma unroll
    for (int f = 0; f < 12; ++f) {
      float v = bf2f(hs[(size_t)(f * BSZ + b) * HID + 3 * n + kk]);
      v = fmaxf(v, 0.0f);
      int j = 12 * kk + f;
#pragma unroll
      for (int o = 0; o < 12; ++o) acc[o] += v * Wsh[o * 36 + j];
    }

#pragma unroll
  for (int o = 0; o < 12; ++o) out[(size_t)idx * 12 + o] = acc[o];
}

extern "C" void kernel_launch(void* const* d_in, const int* in_sizes, int n_in,
                              void* d_out, int out_size, void* d_ws, size_t ws_size,
                              hipStream_t stream) {
  (void)in_sizes; (void)n_in; (void)out_size; (void)ws_size;
  const float* X     = (const float*)d_in[1];
  const float* W_ih  = (const float*)d_in[2];
  const float* W_hh  = (const float*)d_in[3];
  const float* b_ih  = (const float*)d_in[4];
  const float* b_hh  = (const float*)d_in[5];
  const float* lin_W = (const float*)d_in[6];
  const float* lin_b = (const float*)d_in[7];
  float* out = (float*)d_out;

  char* p = (char*)d_ws;
  u16*   Ax   = (u16*)p;   p += (size_t)MROWS * INSZ * 2;
  u16*   Wihb = (u16*)p;   p += (size_t)GATES * INSZ * 2;
  u16*   Whhb = (u16*)p;   p += (size_t)GATES * HID * 2;
  u16*   XW   = (u16*)p;   p += (size_t)MROWS * GATES * 2;   // bf16 gates
  float* cbuf = (float*)p; p += (size_t)BSZ * HID * 4;
  u16*   hs   = (u16*)p;   p += (size_t)FF * BSZ * HID * 2;  // bf16 h ring + output

  hipFuncSetAttribute((const void*)gemm8p,
                      hipFuncAttributeMaxDynamicSharedMemorySize, LDS_TOTAL);

  // 1) convert weights (gate-interleaved rows) + pack X
  cvt_perm<<<(GATES * (INSZ / 4)) / 256, 256, 0, stream>>>(W_ih, Wihb, INSZ / 4);
  cvt_perm<<<(GATES * (HID / 4)) / 256, 256, 0, stream>>>(W_hh, Whhb, HID / 4);
  pack_x4<<<(BSZ * INSZ / 4) / 256, 256, 0, stream>>>(X, Ax);

  // 2) hoisted input GEMM: XW (bf16, interleaved cols) = Ax @ Wihb^T + biases
  gemm8p<<<256, 512, LDS_TOTAL, stream>>>(Ax, Wihb, b_ih, b_hh, XW,
                                          MROWS, GATES, INSZ);

  // 3) recurrence: fused GEMM+cell per step; h ring = bf16 hs slices
  const size_t S = (size_t)BSZ * HID;
  cell_first<<<(BSZ * HID) / 256, 256, 0, stream>>>(XW, cbuf, hs);
  for (int f = 1; f < FF; ++f) {
    gemm_cell<<<768, 256, 0, stream>>>(
        hs + (f - 1) * S, Whhb, XW + (size_t)f * BSZ * GATES, cbuf, hs + f * S);
  }

  // 4) final linear
  final_k<<<(BSZ * NN) / 256, 256, 0, stream>>>(hs, lin_W, lin_b, out);
}

// Round 21
// 416.117 us; speedup vs baseline: 1.0277x; 1.0025x over previous
//
#include <hip/hip_runtime.h>
#include <hip/hip_bf16.h>
#include <stdint.h>

typedef uint16_t u16;
typedef __attribute__((ext_vector_type(8))) __bf16 bf16x8;
typedef __attribute__((ext_vector_type(4))) float f32x4;
typedef __attribute__((ext_vector_type(4))) u16 u16x4;

// Problem constants
#define BSZ   256
#define NN    512
#define TT    12
#define FF    12
#define HID   1536
#define INSZ  6144    // N*F = LSTM input size
#define GATES 6144    // 4*HID
#define MROWS 3072    // FF*BSZ rows of the hoisted input GEMM

static __device__ __forceinline__ u16 f2bf(float x) {
  uint32_t u = __builtin_bit_cast(uint32_t, x);
  u += 0x7fffu + ((u >> 16) & 1u);   // RNE
  return (u16)(u >> 16);
}

static __device__ __forceinline__ float bf2f(u16 x) {
  return __builtin_bit_cast(float, (uint32_t)x << 16);
}

static __device__ __forceinline__ float sigm(float x) {
  return 1.0f / (1.0f + expf(-x));
}

// ---------------- fp32 -> bf16 convert + gate-interleave row permute ----------------
// out row' = 4*(r%HID) + r/HID  (orig row r = g*HID + j  ->  row' = 4j+g)
__global__ void cvt_perm(const float* __restrict__ in, u16* __restrict__ out,
                         int ncol4) {
  long idx = (long)blockIdx.x * blockDim.x + threadIdx.x;   // r*ncol4 + c4
  int r  = (int)(idx / ncol4);
  int c4 = (int)(idx - (long)r * ncol4);
  int rp = ((r % HID) << 2) + r / HID;
  float4 v = ((const float4*)in)[idx];
  u16x4 w = { f2bf(v.x), f2bf(v.y), f2bf(v.z), f2bf(v.w) };
  ((u16x4*)out)[(size_t)rp * ncol4 + c4] = w;
}

// ---------------- pack X: 4 k's per thread -> coalesced u16x4 writes ----------------
__global__ void pack_x4(const float* __restrict__ X, u16* __restrict__ Ax) {
  int idx = blockIdx.x * blockDim.x + threadIdx.x;   // (b, k4), k4 in [0,1536)
  int b  = idx / (INSZ / 4);
  int k4 = idx - b * (INSZ / 4);
  const float* xp = X + (size_t)b * (INSZ * FF) + (size_t)k4 * (4 * FF);
  float4 v[12];   // 48 floats = [kk 0..3][f 0..11]
#pragma unroll
  for (int j = 0; j < 12; ++j) v[j] = ((const float4*)xp)[j];
  const float* vf = (const float*)v;
#pragma unroll
  for (int f = 0; f < FF; ++f) {
    u16x4 w = { f2bf(vf[0 * FF + f]), f2bf(vf[1 * FF + f]),
                f2bf(vf[2 * FF + f]), f2bf(vf[3 * FF + f]) };
    *(u16x4*)&Ax[(size_t)(f * BSZ + b) * INSZ + k4 * 4] = w;
  }
}

// =====================================================================
// Deep-pipelined bf16 GEMM (R16 deferral structure, bf16 C out).
// R21: XCD mapping flipped — XCD x owns n-tiles {2x,2x+1} x ALL 16
// m-tiles. Per-XCD unique B drops 75.5->9.4 MB (fits L2, all 16
// co-resident m-blocks share the same two B K-slabs per step); A
// streams once. Cuts FETCH over-fetch and shortens vmcnt stalls.
// Tile 192x384, BK=64, 8 waves (2x4), 2 barriers/K-tile.
// =====================================================================
#define BM8 192
#define BN8 384
#define LDSA_SZ 24576
#define LDSB_SZ 49152
#define LDS_TOTAL (2 * (LDSA_SZ + LDSB_SZ))   // 147456

#define GLL(src, dst)                                                          \
  __builtin_amdgcn_global_load_lds(                                            \
      (const __attribute__((address_space(1))) void*)(src),                    \
      (__attribute__((address_space(3))) void*)(dst), 16, 0, 0)

#define SBAR() asm volatile("s_barrier" ::: "memory")
#define SCHED_FENCE_DS() __builtin_amdgcn_sched_barrier(0x7F)
#define WAIT_LGKM0()                                                           \
  do {                                                                         \
    asm volatile("s_waitcnt lgkmcnt(0)" ::: "memory");                         \
    __builtin_amdgcn_sched_barrier(0);                                         \
  } while (0)

#define MFMA9(AF, BF, RO, CO)                                                  \
  do {                                                                         \
    __builtin_amdgcn_s_setprio(1);                                             \
    _Pragma("unroll") for (int i = 0; i < 3; ++i)                              \
        _Pragma("unroll") for (int j = 0; j < 3; ++j)                          \
            acc[RO + i][CO + j] = __builtin_amdgcn_mfma_f32_16x16x32_bf16(     \
                AF[i], BF[j], acc[RO + i][CO + j], 0, 0, 0);                   \
    __builtin_amdgcn_s_setprio(0);                                             \
  } while (0)

__global__ __launch_bounds__(512, 1) void gemm8p(
    const u16* __restrict__ A, const u16* __restrict__ Bt,
    const float* __restrict__ bi, const float* __restrict__ bh,
    u16* __restrict__ C, int M, int N, int K) {
  extern __shared__ __align__(16) char lds[];
  const int tid  = threadIdx.x;
  const int lane = tid & 63;
  const int wid  = tid >> 6;
  const int wr   = wid >> 2;
  const int wc   = wid & 3;

  // R21 XCD mapping: xcd = orig&7 owns n-tiles {2x,2x+1} x all 16 m-tiles
  const int orig = blockIdx.x;
  const int xcd  = orig & 7;
  const int jj   = orig >> 3;               // 0..31
  const int m0   = (jj & 15) * BM8;
  const int n0   = (2 * xcd + (jj >> 4)) * BN8;

  const int fr    = lane & 15;
  const int kb    = (lane >> 4) << 4;
  const int swz   = (fr & 7) << 4;
  const int colp0 = kb ^ swz;
  const int colp1 = (64 | kb) ^ swz;

  const int srow = tid >> 3;
  const int scb  = ((tid & 7) << 4) ^ ((srow & 7) << 4);
  const u16* gA = A  + (size_t)(m0 + srow) * K + (scb >> 1);
  const u16* gB = Bt + (size_t)(n0 + srow) * K + (scb >> 1);
  const int wdst = wid << 10;

  char* ldsA = lds;
  char* ldsB = lds + 2 * LDSA_SZ;
  char* aRowB = ldsA + (wr * 96 + fr) * 128;
  char* bRowB = ldsB + (wc * 96 + fr) * 128;

  f32x4 acc[6][6] = {};
  const int NT = K >> 6;

#pragma unroll
  for (int c = 0; c < 3; ++c) GLL(gA + (size_t)c * 64 * K, ldsA + c * 8192 + wdst);
#pragma unroll
  for (int c = 0; c < 6; ++c) GLL(gB + (size_t)c * 64 * K, ldsB + c * 8192 + wdst);

  bf16x8 a1o[3], b1o[3], b0o[3];   // deferred operands from previous tile

  for (int t = 0; t < NT; ++t) {
    const int p = t & 1;
    char* aRow = aRowB + p * LDSA_SZ;
    char* bRow = bRowB + p * LDSB_SZ;
    char* An = ldsA + (p ^ 1) * LDSA_SZ;
    char* Bn = ldsB + (p ^ 1) * LDSB_SZ;
    const u16* gAn = gA + (size_t)(t + 1) * 64;
    const u16* gBn = gB + (size_t)(t + 1) * 64;
    const bool pf = (t + 1 < NT);

    bf16x8 a0k0[3], b0k0[3], b1k0[3], a1k0[3];
    bf16x8 a0k1[3], b0k1[3], b1k1[3], a1k1[3];

    if (pf) {
#pragma unroll
      for (int c = 0; c < 3; ++c) GLL(gAn + (size_t)c * 64 * K, An + c * 8192 + wdst);
      asm volatile("s_waitcnt vmcnt(3)" ::: "memory");
    } else {
      asm volatile("s_waitcnt vmcnt(0)" ::: "memory");
    }
    SBAR();

    // ---- p0: R a0k0 + b0k0 ; deferred q11(old)
#pragma unroll
    for (int i = 0; i < 3; ++i) {
      a0k0[i] = *(const bf16x8*)(aRow + i * 2048 + colp0);
      b0k0[i] = *(const bf16x8*)(bRow + i * 2048 + colp0);
    }
    if (t > 0) MFMA9(a1o, b1o, 3, 3);
    SCHED_FENCE_DS();

    // ---- p1: R b1k0 ; deferred q10(old) ; GLL B01
#pragma unroll
    for (int i = 0; i < 3; ++i) b1k0[i] = *(const bf16x8*)(bRow + (3 + i) * 2048 + colp0);
    if (t > 0) MFMA9(a1o, b0o, 3, 0);
    if (pf) {
      GLL(gBn + (size_t)0 * 64 * K, Bn + 0 * 8192 + wdst);
      GLL(gBn + (size_t)1 * 64 * K, Bn + 1 * 8192 + wdst);
    }
    SCHED_FENCE_DS();

    // ---- p2: R a1k0 ; q00k0 ; GLL B23
#pragma unroll
    for (int i = 0; i < 3; ++i) a1k0[i] = *(const bf16x8*)(aRow + (3 + i) * 2048 + colp0);
    MFMA9(a0k0, b0k0, 0, 0);
    if (pf) {
      GLL(gBn + (size_t)2 * 64 * K, Bn + 2 * 8192 + wdst);
      GLL(gBn + (size_t)3 * 64 * K, Bn + 3 * 8192 + wdst);
    }
    SCHED_FENCE_DS();

    // ---- p3: R a0k1 ; q01k0 ; GLL B45
#pragma unroll
    for (int i = 0; i < 3; ++i) a0k1[i] = *(const bf16x8*)(aRow + i * 2048 + colp1);
    MFMA9(a0k0, b1k0, 0, 3);
    if (pf) {
      GLL(gBn + (size_t)4 * 64 * K, Bn + 4 * 8192 + wdst);
      GLL(gBn + (size_t)5 * 64 * K, Bn + 5 * 8192 + wdst);
    }
    SCHED_FENCE_DS();

    // ---- p4: R b0k1 ; q11k0
#pragma unroll
    for (int i = 0; i < 3; ++i) b0k1[i] = *(const bf16x8*)(bRow + i * 2048 + colp1);
    MFMA9(a1k0, b1k0, 3, 3);
    SCHED_FENCE_DS();

    // ---- p5: R b1k1 ; q10k0
#pragma unroll
    for (int i = 0; i < 3; ++i) b1k1[i] = *(const bf16x8*)(bRow + (3 + i) * 2048 + colp1);
    MFMA9(a1k0, b0k0, 3, 0);
    SCHED_FENCE_DS();

    // ---- p6: R a1k1 ; q00k1
#pragma unroll
    for (int i = 0; i < 3; ++i) a1k1[i] = *(const bf16x8*)(aRow + (3 + i) * 2048 + colp1);
    MFMA9(a0k1, b0k1, 0, 0);
    SCHED_FENCE_DS();

    // ---- p7: q01k1 ; save deferred operands (q11k1/q10k1 run next iter)
    MFMA9(a0k1, b1k1, 0, 3);
#pragma unroll
    for (int i = 0; i < 3; ++i) { a1o[i] = a1k1[i]; b1o[i] = b1k1[i]; b0o[i] = b0k1[i]; }

    // drain this wave's ds_reads of buffer p before any wave overwrites p
    asm volatile("s_waitcnt lgkmcnt(0)" ::: "memory");
    SBAR();
  }

  // drain deferred clusters of the final tile
  MFMA9(a1o, b1o, 3, 3);
  MFMA9(a1o, b0o, 3, 0);

  const int r0 = (lane >> 4) << 2;
  const int cc = lane & 15;
#pragma unroll
  for (int j = 0; j < 6; ++j) {
    const int col = n0 + wc * 96 + j * 16 + cc;          // interleaved position
    const int oc  = (col & 3) * HID + (col >> 2);        // original gate index
    const float bv = bi[oc] + bh[oc];
#pragma unroll
    for (int i = 0; i < 6; ++i) {
      const size_t rbase = (size_t)(m0 + wr * 96 + i * 16 + r0) * N + col;
#pragma unroll
      for (int r = 0; r < 4; ++r)
        C[rbase + (size_t)r * N] = f2bf(acc[i][j][r] + bv);
    }
  }
}

// =====================================================================
// Fused step (R16 structure; XW bf16).
// 32x64 tile, 768 blocks, BK=64, dbuf 24KB, vmcnt(3), XCD mapping.
// =====================================================================
__global__ __launch_bounds__(256, 4) void gemm_cell(
    const u16* __restrict__ hs_in,     // (256 x 1536) bf16 h(t-1) = hs[f-1]
    const u16* __restrict__ Whhb,      // (6144 x 1536) bf16, rows interleaved
    const u16* __restrict__ XW_b,      // (256 x 6144) bf16 interleaved, biases in
    float* __restrict__ cbuf,          // (256 x 1536) c state (in-place)
    u16* __restrict__ hs_out) {        // (256 x 1536) bf16 h(t) = hs[f]
  __shared__ __align__(16) char lds[24576];   // A dbuf 2x4K + B dbuf 2x8K
  const int tid  = threadIdx.x;
  const int lane = tid & 63;
  const int wid  = tid >> 6;
  const int wr   = wid >> 1;   // 0..1 (m half: 16 rows)
  const int wc   = wid & 1;    // 0..1 (n half: 32 cols)

  // XCD-aware mapping (bijective): xcd = orig&7, jj = orig>>3 in [0,96):
  // n-tile = 12*xcd + jj>>3, m-tile = jj&7.
  const int orig = blockIdx.x;
  const int xcd  = orig & 7;
  const int jj   = orig >> 3;
  const int n0   = (12 * xcd + (jj >> 3)) * 64;   // interleaved col base
  const int m0   = (jj & 7) * 32;                 // batch base
  const int K    = HID;

  const int fr    = lane & 15;
  const int kb    = (lane >> 4) << 4;
  const int swz   = (fr & 7) << 4;
  const int colp0 = kb ^ swz;
  const int colp1 = (64 | kb) ^ swz;

  const int srow = tid >> 3;
  const int scb  = ((tid & 7) << 4) ^ ((srow & 7) << 4);
  const u16* gA = hs_in + (size_t)(m0 + srow) * K + (scb >> 1);
  const u16* gB = Whhb  + (size_t)(n0 + srow) * K + (scb >> 1);
  const int wdst = wid << 10;

  char* ldsA = lds;            // [2][4096]  (32 rows x 128B)
  char* ldsB = lds + 8192;     // [2][8192]  (64 rows x 128B)
  char* aRowB = ldsA + (wr * 16 + fr) * 128;
  char* bRowB = ldsB + (wc * 32 + fr) * 128;

  f32x4 acc[2] = {};
  const int NT = K >> 6;   // 24

  GLL(gA,                  ldsA + wdst);
  GLL(gB,                  ldsB + wdst);
  GLL(gB + (size_t)32 * K, ldsB + 4096 + wdst);

  for (int t = 0; t < NT; ++t) {
    const int p = t & 1;
    char* aRow = aRowB + p * 4096;
    char* bRow = bRowB + p * 8192;
    char* An = ldsA + (p ^ 1) * 4096;
    char* Bn = ldsB + (p ^ 1) * 8192;
    const u16* gAn = gA + (size_t)(t + 1) * 64;
    const u16* gBn = gB + (size_t)(t + 1) * 64;

    if (t + 1 < NT) {
      GLL(gAn,                  An + wdst);
      GLL(gBn,                  Bn + wdst);
      GLL(gBn + (size_t)32 * K, Bn + 4096 + wdst);
      asm volatile("s_waitcnt vmcnt(3)" ::: "memory");
    } else {
      asm volatile("s_waitcnt vmcnt(0)" ::: "memory");
    }
    SBAR();

    bf16x8 a[2], b[2][2];
    a[0] = *(const bf16x8*)(aRow + colp0);
    a[1] = *(const bf16x8*)(aRow + colp1);
#pragma unroll
    for (int j = 0; j < 2; ++j) {
      b[0][j] = *(const bf16x8*)(bRow + j * 2048 + colp0);
      b[1][j] = *(const bf16x8*)(bRow + j * 2048 + colp1);
    }
    WAIT_LGKM0();
    __builtin_amdgcn_s_setprio(1);
#pragma unroll
    for (int k = 0; k < 2; ++k)
#pragma unroll
      for (int j = 0; j < 2; ++j)
        acc[j] = __builtin_amdgcn_mfma_f32_16x16x32_bf16(a[k], b[k][j], acc[j], 0, 0, 0);
    __builtin_amdgcn_s_setprio(0);
    SBAR();
  }

  // ---- epilogue: acc -> LDS (stride 68 floats kills bank conflicts) ----
  float* sacc = (float*)lds;   // [32][68] = 8704 B, gemm bufs dead
  const int r0 = (lane >> 4) << 2;
  const int cc = lane & 15;
#pragma unroll
  for (int j = 0; j < 2; ++j) {
    const int ml = wr * 16 + r0;
    const int nl = wc * 32 + j * 16 + cc;
#pragma unroll
    for (int r = 0; r < 4; ++r)
      sacc[(ml + r) * 68 + nl] = acc[j][r];
  }
  __syncthreads();

  // ---- cell: 32 batch x 16 j's; gates i,f,g,o = interleaved cols 4j+0..3
  for (int it = tid; it < 512; it += 256) {
    const int bl = it >> 4;                 // local batch 0..31
    const int jl = it & 15;                 // local j 0..15
    const int b  = m0 + bl;
    const int jg = (n0 >> 2) + jl;          // global j
    const float4 hw = *(const float4*)&sacc[bl * 68 + jl * 4];
    const u16x4 xq = *(const u16x4*)&XW_b[(size_t)b * GATES + n0 + jl * 4];
    const float gi = bf2f(xq.x) + hw.x;
    const float gf = bf2f(xq.y) + hw.y;
    const float gg = bf2f(xq.z) + hw.z;
    const float go = bf2f(xq.w) + hw.w;
    const int cidx = b * HID + jg;
    const float cp = cbuf[cidx];
    const float cv = sigm(gf) * cp + sigm(gi) * tanhf(gg);
    const float h  = tanhf(sigm(go) * tanhf(cv));
    cbuf[cidx]   = cv;
    hs_out[cidx] = f2bf(h);
  }
}

// ---------------- first step: gates = XW' only (biases included) ----------------
__global__ void cell_first(const u16* __restrict__ XW,
                           float* __restrict__ cbuf,
                           u16* __restrict__ hs_out) {
  int it = blockIdx.x * blockDim.x + threadIdx.x;   // 256*1536 items
  int b = it / HID;
  int j = it - b * HID;
  const u16x4 xq = *(const u16x4*)&XW[(size_t)b * GATES + 4 * j];
  const float cv = sigm(bf2f(xq.x)) * tanhf(bf2f(xq.z));
  const float h  = tanhf(sigm(bf2f(xq.w)) * tanhf(cv));
  cbuf[it]   = cv;
  hs_out[it] = f2bf(h);
}

// ---------------- final: out[b,n,o] = relu(out2[b,n,:]) @ lin_W^T + lin_b ----------------
__global__ __launch_bounds__(256) void final_k(const u16* __restrict__ hs,
                                               const float* __restrict__ lin_W,
                                               const float* __restrict__ lin_b,
                                               float* __restrict__ out) {
  __shared__ float Wsh[12 * 36];
  __shared__ float bsh[12];
  for (int i = threadIdx.x; i < 12 * 36; i += blockDim.x) Wsh[i] = lin_W[i];
  if (threadIdx.x < 12) bsh[threadIdx.x] = lin_b[threadIdx.x];
  __syncthreads();

  int idx = blockIdx.x * blockDim.x + threadIdx.x;
  int b = idx >> 9;
  int n = idx & 511;

  float acc[12];
#pragma unroll
  for (int o = 0; o < 12; ++o) acc[o] = bsh[o];

#pragma unroll
  for (int kk = 0; kk < 3; ++kk)
#pragma unroll
    for (int f = 0; f < 12; ++f) {
      float v = bf2f(hs[(size_t)(f * BSZ + b) * HID + 3 * n + kk]);
      v = fmaxf(v, 0.0f);
      int j = 12 * kk + f;
#pragma unroll
      for (int o = 0; o < 12; ++o) acc[o] += v * Wsh[o * 36 + j];
    }

#pragma unroll
  for (int o = 0; o < 12; ++o) out[(size_t)idx * 12 + o] = acc[o];
}

extern "C" void kernel_launch(void* const* d_in, const int* in_sizes, int n_in,
                              void* d_out, int out_size, void* d_ws, size_t ws_size,
                              hipStream_t stream) {
  (void)in_sizes; (void)n_in; (void)out_size; (void)ws_size;
  const float* X     = (const float*)d_in[1];
  const float* W_ih  = (const float*)d_in[2];
  const float* W_hh  = (const float*)d_in[3];
  const float* b_ih  = (const float*)d_in[4];
  const float* b_hh  = (const float*)d_in[5];
  const float* lin_W = (const float*)d_in[6];
  const float* lin_b = (const float*)d_in[7];
  float* out = (float*)d_out;

  char* p = (char*)d_ws;
  u16*   Ax   = (u16*)p;   p += (size_t)MROWS * INSZ * 2;
  u16*   Wihb = (u16*)p;   p += (size_t)GATES * INSZ * 2;
  u16*   Whhb = (u16*)p;   p += (size_t)GATES * HID * 2;
  u16*   XW   = (u16*)p;   p += (size_t)MROWS * GATES * 2;   // bf16 gates
  float* cbuf = (float*)p; p += (size_t)BSZ * HID * 4;
  u16*   hs   = (u16*)p;   p += (size_t)FF * BSZ * HID * 2;  // bf16 h ring + output

  hipFuncSetAttribute((const void*)gemm8p,
                      hipFuncAttributeMaxDynamicSharedMemorySize, LDS_TOTAL);

  // 1) convert weights (gate-interleaved rows) + pack X
  cvt_perm<<<(GATES * (INSZ / 4)) / 256, 256, 0, stream>>>(W_ih, Wihb, INSZ / 4);
  cvt_perm<<<(GATES * (HID / 4)) / 256, 256, 0, stream>>>(W_hh, Whhb, HID / 4);
  pack_x4<<<(BSZ * INSZ / 4) / 256, 256, 0, stream>>>(X, Ax);

  // 2) hoisted input GEMM: XW (bf16, interleaved cols) = Ax @ Wihb^T + biases
  gemm8p<<<256, 512, LDS_TOTAL, stream>>>(Ax, Wihb, b_ih, b_hh, XW,
                                          MROWS, GATES, INSZ);

  // 3) recurrence: fused GEMM+cell per step; h ring = bf16 hs slices
  const size_t S = (size_t)BSZ * HID;
  cell_first<<<(BSZ * HID) / 256, 256, 0, stream>>>(XW, cbuf, hs);
  for (int f = 1; f < FF; ++f) {
    gemm_cell<<<768, 256, 0, stream>>>(
        hs + (f - 1) * S, Whhb, XW + (size_t)f * BSZ * GATES, cbuf, hs + f * S);
  }

  // 4) final linear
  final_k<<<(BSZ * NN) / 256, 256, 0, stream>>>(hs, lin_W, lin_b, out);
}

// Round 22
// 414.888 us; speedup vs baseline: 1.0308x; 1.0030x over previous
//
#include <hip/hip_runtime.h>
#include <hip/hip_bf16.h>
#include <stdint.h>

typedef uint16_t u16;
typedef __attribute__((ext_vector_type(8))) __bf16 bf16x8;
typedef __attribute__((ext_vector_type(4))) float f32x4;
typedef __attribute__((ext_vector_type(4))) u16 u16x4;

// Problem constants
#define BSZ   256
#define NN    512
#define TT    12
#define FF    12
#define HID   1536
#define INSZ  6144    // N*F = LSTM input size
#define GATES 6144    // 4*HID
#define MROWS 3072    // FF*BSZ rows of the hoisted input GEMM

static __device__ __forceinline__ u16 f2bf(float x) {
  uint32_t u = __builtin_bit_cast(uint32_t, x);
  u += 0x7fffu + ((u >> 16) & 1u);   // RNE
  return (u16)(u >> 16);
}

static __device__ __forceinline__ float bf2f(u16 x) {
  return __builtin_bit_cast(float, (uint32_t)x << 16);
}

static __device__ __forceinline__ float sigm(float x) {
  return 1.0f / (1.0f + expf(-x));
}

// ---------------- fp32 -> bf16 convert + gate-interleave row permute ----------------
// out row' = 4*(r%HID) + r/HID  (orig row r = g*HID + j  ->  row' = 4j+g)
__global__ void cvt_perm(const float* __restrict__ in, u16* __restrict__ out,
                         int ncol4) {
  long idx = (long)blockIdx.x * blockDim.x + threadIdx.x;   // r*ncol4 + c4
  int r  = (int)(idx / ncol4);
  int c4 = (int)(idx - (long)r * ncol4);
  int rp = ((r % HID) << 2) + r / HID;
  float4 v = ((const float4*)in)[idx];
  u16x4 w = { f2bf(v.x), f2bf(v.y), f2bf(v.z), f2bf(v.w) };
  ((u16x4*)out)[(size_t)rp * ncol4 + c4] = w;
}

// ---------------- pack X: 4 k's per thread -> coalesced u16x4 writes ----------------
__global__ void pack_x4(const float* __restrict__ X, u16* __restrict__ Ax) {
  int idx = blockIdx.x * blockDim.x + threadIdx.x;   // (b, k4), k4 in [0,1536)
  int b  = idx / (INSZ / 4);
  int k4 = idx - b * (INSZ / 4);
  const float* xp = X + (size_t)b * (INSZ * FF) + (size_t)k4 * (4 * FF);
  float4 v[12];   // 48 floats = [kk 0..3][f 0..11]
#pragma unroll
  for (int j = 0; j < 12; ++j) v[j] = ((const float4*)xp)[j];
  const float* vf = (const float*)v;
#pragma unroll
  for (int f = 0; f < FF; ++f) {
    u16x4 w = { f2bf(vf[0 * FF + f]), f2bf(vf[1 * FF + f]),
                f2bf(vf[2 * FF + f]), f2bf(vf[3 * FF + f]) };
    *(u16x4*)&Ax[(size_t)(f * BSZ + b) * INSZ + k4 * 4] = w;
  }
}

// =====================================================================
// Deep-pipelined bf16 GEMM (R16 deferral structure, bf16 C out,
// R20 XCD swizzle restored — R21's n-panel mapping regressed).
// Tile 192x384, BK=64, 8 waves (2x4), 2 barriers/K-tile.
// =====================================================================
#define BM8 192
#define BN8 384
#define LDSA_SZ 24576
#define LDSB_SZ 49152
#define LDS_TOTAL (2 * (LDSA_SZ + LDSB_SZ))   // 147456

#define GLL(src, dst)                                                          \
  __builtin_amdgcn_global_load_lds(                                            \
      (const __attribute__((address_space(1))) void*)(src),                    \
      (__attribute__((address_space(3))) void*)(dst), 16, 0, 0)

#define SBAR() asm volatile("s_barrier" ::: "memory")
#define SCHED_FENCE_DS() __builtin_amdgcn_sched_barrier(0x7F)
#define WAIT_LGKM0()                                                           \
  do {                                                                         \
    asm volatile("s_waitcnt lgkmcnt(0)" ::: "memory");                         \
    __builtin_amdgcn_sched_barrier(0);                                         \
  } while (0)

#define MFMA9(AF, BF, RO, CO)                                                  \
  do {                                                                         \
    __builtin_amdgcn_s_setprio(1);                                             \
    _Pragma("unroll") for (int i = 0; i < 3; ++i)                              \
        _Pragma("unroll") for (int j = 0; j < 3; ++j)                          \
            acc[RO + i][CO + j] = __builtin_amdgcn_mfma_f32_16x16x32_bf16(     \
                AF[i], BF[j], acc[RO + i][CO + j], 0, 0, 0);                   \
    __builtin_amdgcn_s_setprio(0);                                             \
  } while (0)

__global__ __launch_bounds__(512, 1) void gemm8p(
    const u16* __restrict__ A, const u16* __restrict__ Bt,
    const float* __restrict__ bi, const float* __restrict__ bh,
    u16* __restrict__ C, int M, int N, int K) {
  extern __shared__ __align__(16) char lds[];
  const int tid  = threadIdx.x;
  const int lane = tid & 63;
  const int wid  = tid >> 6;
  const int wr   = wid >> 2;
  const int wc   = wid & 3;

  // R20 XCD swizzle (proven): wgid = (orig&7)*cpx + orig>>3
  const int nbx  = N / BN8;
  const int cpx  = gridDim.x >> 3;
  const int orig = blockIdx.x;
  const int wgid = (orig & 7) * cpx + (orig >> 3);
  const int m0   = (wgid / nbx) * BM8;
  const int n0   = (wgid % nbx) * BN8;

  const int fr    = lane & 15;
  const int kb    = (lane >> 4) << 4;
  const int swz   = (fr & 7) << 4;
  const int colp0 = kb ^ swz;
  const int colp1 = (64 | kb) ^ swz;

  const int srow = tid >> 3;
  const int scb  = ((tid & 7) << 4) ^ ((srow & 7) << 4);
  const u16* gA = A  + (size_t)(m0 + srow) * K + (scb >> 1);
  const u16* gB = Bt + (size_t)(n0 + srow) * K + (scb >> 1);
  const int wdst = wid << 10;

  char* ldsA = lds;
  char* ldsB = lds + 2 * LDSA_SZ;
  char* aRowB = ldsA + (wr * 96 + fr) * 128;
  char* bRowB = ldsB + (wc * 96 + fr) * 128;

  f32x4 acc[6][6] = {};
  const int NT = K >> 6;

#pragma unroll
  for (int c = 0; c < 3; ++c) GLL(gA + (size_t)c * 64 * K, ldsA + c * 8192 + wdst);
#pragma unroll
  for (int c = 0; c < 6; ++c) GLL(gB + (size_t)c * 64 * K, ldsB + c * 8192 + wdst);

  bf16x8 a1o[3], b1o[3], b0o[3];   // deferred operands from previous tile

  for (int t = 0; t < NT; ++t) {
    const int p = t & 1;
    char* aRow = aRowB + p * LDSA_SZ;
    char* bRow = bRowB + p * LDSB_SZ;
    char* An = ldsA + (p ^ 1) * LDSA_SZ;
    char* Bn = ldsB + (p ^ 1) * LDSB_SZ;
    const u16* gAn = gA + (size_t)(t + 1) * 64;
    const u16* gBn = gB + (size_t)(t + 1) * 64;
    const bool pf = (t + 1 < NT);

    bf16x8 a0k0[3], b0k0[3], b1k0[3], a1k0[3];
    bf16x8 a0k1[3], b0k1[3], b1k1[3], a1k1[3];

    if (pf) {
#pragma unroll
      for (int c = 0; c < 3; ++c) GLL(gAn + (size_t)c * 64 * K, An + c * 8192 + wdst);
      asm volatile("s_waitcnt vmcnt(3)" ::: "memory");
    } else {
      asm volatile("s_waitcnt vmcnt(0)" ::: "memory");
    }
    SBAR();

    // ---- p0: R a0k0 + b0k0 ; deferred q11(old)
#pragma unroll
    for (int i = 0; i < 3; ++i) {
      a0k0[i] = *(const bf16x8*)(aRow + i * 2048 + colp0);
      b0k0[i] = *(const bf16x8*)(bRow + i * 2048 + colp0);
    }
    if (t > 0) MFMA9(a1o, b1o, 3, 3);
    SCHED_FENCE_DS();

    // ---- p1: R b1k0 ; deferred q10(old) ; GLL B01
#pragma unroll
    for (int i = 0; i < 3; ++i) b1k0[i] = *(const bf16x8*)(bRow + (3 + i) * 2048 + colp0);
    if (t > 0) MFMA9(a1o, b0o, 3, 0);
    if (pf) {
      GLL(gBn + (size_t)0 * 64 * K, Bn + 0 * 8192 + wdst);
      GLL(gBn + (size_t)1 * 64 * K, Bn + 1 * 8192 + wdst);
    }
    SCHED_FENCE_DS();

    // ---- p2: R a1k0 ; q00k0 ; GLL B23
#pragma unroll
    for (int i = 0; i < 3; ++i) a1k0[i] = *(const bf16x8*)(aRow + (3 + i) * 2048 + colp0);
    MFMA9(a0k0, b0k0, 0, 0);
    if (pf) {
      GLL(gBn + (size_t)2 * 64 * K, Bn + 2 * 8192 + wdst);
      GLL(gBn + (size_t)3 * 64 * K, Bn + 3 * 8192 + wdst);
    }
    SCHED_FENCE_DS();

    // ---- p3: R a0k1 ; q01k0 ; GLL B45
#pragma unroll
    for (int i = 0; i < 3; ++i) a0k1[i] = *(const bf16x8*)(aRow + i * 2048 + colp1);
    MFMA9(a0k0, b1k0, 0, 3);
    if (pf) {
      GLL(gBn + (size_t)4 * 64 * K, Bn + 4 * 8192 + wdst);
      GLL(gBn + (size_t)5 * 64 * K, Bn + 5 * 8192 + wdst);
    }
    SCHED_FENCE_DS();

    // ---- p4: R b0k1 ; q11k0
#pragma unroll
    for (int i = 0; i < 3; ++i) b0k1[i] = *(const bf16x8*)(bRow + i * 2048 + colp1);
    MFMA9(a1k0, b1k0, 3, 3);
    SCHED_FENCE_DS();

    // ---- p5: R b1k1 ; q10k0
#pragma unroll
    for (int i = 0; i < 3; ++i) b1k1[i] = *(const bf16x8*)(bRow + (3 + i) * 2048 + colp1);
    MFMA9(a1k0, b0k0, 3, 0);
    SCHED_FENCE_DS();

    // ---- p6: R a1k1 ; q00k1
#pragma unroll
    for (int i = 0; i < 3; ++i) a1k1[i] = *(const bf16x8*)(aRow + (3 + i) * 2048 + colp1);
    MFMA9(a0k1, b0k1, 0, 0);
    SCHED_FENCE_DS();

    // ---- p7: q01k1 ; save deferred operands (q11k1/q10k1 run next iter)
    MFMA9(a0k1, b1k1, 0, 3);
#pragma unroll
    for (int i = 0; i < 3; ++i) { a1o[i] = a1k1[i]; b1o[i] = b1k1[i]; b0o[i] = b0k1[i]; }

    // drain this wave's ds_reads of buffer p before any wave overwrites p
    asm volatile("s_waitcnt lgkmcnt(0)" ::: "memory");
    SBAR();
  }

  // drain deferred clusters of the final tile
  MFMA9(a1o, b1o, 3, 3);
  MFMA9(a1o, b0o, 3, 0);

  const int r0 = (lane >> 4) << 2;
  const int cc = lane & 15;
#pragma unroll
  for (int j = 0; j < 6; ++j) {
    const int col = n0 + wc * 96 + j * 16 + cc;          // interleaved position
    const int oc  = (col & 3) * HID + (col >> 2);        // original gate index
    const float bv = bi[oc] + bh[oc];
#pragma unroll
    for (int i = 0; i < 6; ++i) {
      const size_t rbase = (size_t)(m0 + wr * 96 + i * 16 + r0) * N + col;
#pragma unroll
      for (int r = 0; r < 4; ++r)
        C[rbase + (size_t)r * N] = f2bf(acc[i][j][r] + bv);
    }
  }
}

// =====================================================================
// Fused step (R16 structure; XW bf16).
// 32x64 tile, 768 blocks, BK=64, dbuf 24KB, vmcnt(3), XCD mapping.
// =====================================================================
__global__ __launch_bounds__(256, 4) void gemm_cell(
    const u16* __restrict__ hs_in,     // (256 x 1536) bf16 h(t-1) = hs[f-1]
    const u16* __restrict__ Whhb,      // (6144 x 1536) bf16, rows interleaved
    const u16* __restrict__ XW_b,      // (256 x 6144) bf16 interleaved, biases in
    float* __restrict__ cbuf,          // (256 x 1536) c state (in-place)
    u16* __restrict__ hs_out) {        // (256 x 1536) bf16 h(t) = hs[f]
  __shared__ __align__(16) char lds[24576];   // A dbuf 2x4K + B dbuf 2x8K
  const int tid  = threadIdx.x;
  const int lane = tid & 63;
  const int wid  = tid >> 6;
  const int wr   = wid >> 1;   // 0..1 (m half: 16 rows)
  const int wc   = wid & 1;    // 0..1 (n half: 32 cols)

  // XCD-aware mapping (bijective): xcd = orig&7, jj = orig>>3 in [0,96):
  // n-tile = 12*xcd + jj>>3, m-tile = jj&7.
  const int orig = blockIdx.x;
  const int xcd  = orig & 7;
  const int jj   = orig >> 3;
  const int n0   = (12 * xcd + (jj >> 3)) * 64;   // interleaved col base
  const int m0   = (jj & 7) * 32;                 // batch base
  const int K    = HID;

  const int fr    = lane & 15;
  const int kb    = (lane >> 4) << 4;
  const int swz   = (fr & 7) << 4;
  const int colp0 = kb ^ swz;
  const int colp1 = (64 | kb) ^ swz;

  const int srow = tid >> 3;
  const int scb  = ((tid & 7) << 4) ^ ((srow & 7) << 4);
  const u16* gA = hs_in + (size_t)(m0 + srow) * K + (scb >> 1);
  const u16* gB = Whhb  + (size_t)(n0 + srow) * K + (scb >> 1);
  const int wdst = wid << 10;

  char* ldsA = lds;            // [2][4096]  (32 rows x 128B)
  char* ldsB = lds + 8192;     // [2][8192]  (64 rows x 128B)
  char* aRowB = ldsA + (wr * 16 + fr) * 128;
  char* bRowB = ldsB + (wc * 32 + fr) * 128;

  f32x4 acc[2] = {};
  const int NT = K >> 6;   // 24

  GLL(gA,                  ldsA + wdst);
  GLL(gB,                  ldsB + wdst);
  GLL(gB + (size_t)32 * K, ldsB + 4096 + wdst);

  for (int t = 0; t < NT; ++t) {
    const int p = t & 1;
    char* aRow = aRowB + p * 4096;
    char* bRow = bRowB + p * 8192;
    char* An = ldsA + (p ^ 1) * 4096;
    char* Bn = ldsB + (p ^ 1) * 8192;
    const u16* gAn = gA + (size_t)(t + 1) * 64;
    const u16* gBn = gB + (size_t)(t + 1) * 64;

    if (t + 1 < NT) {
      GLL(gAn,                  An + wdst);
      GLL(gBn,                  Bn + wdst);
      GLL(gBn + (size_t)32 * K, Bn + 4096 + wdst);
      asm volatile("s_waitcnt vmcnt(3)" ::: "memory");
    } else {
      asm volatile("s_waitcnt vmcnt(0)" ::: "memory");
    }
    SBAR();

    bf16x8 a[2], b[2][2];
    a[0] = *(const bf16x8*)(aRow + colp0);
    a[1] = *(const bf16x8*)(aRow + colp1);
#pragma unroll
    for (int j = 0; j < 2; ++j) {
      b[0][j] = *(const bf16x8*)(bRow + j * 2048 + colp0);
      b[1][j] = *(const bf16x8*)(bRow + j * 2048 + colp1);
    }
    WAIT_LGKM0();
    __builtin_amdgcn_s_setprio(1);
#pragma unroll
    for (int k = 0; k < 2; ++k)
#pragma unroll
      for (int j = 0; j < 2; ++j)
        acc[j] = __builtin_amdgcn_mfma_f32_16x16x32_bf16(a[k], b[k][j], acc[j], 0, 0, 0);
    __builtin_amdgcn_s_setprio(0);
    SBAR();
  }

  // ---- epilogue: acc -> LDS (stride 68 floats kills bank conflicts) ----
  float* sacc = (float*)lds;   // [32][68] = 8704 B, gemm bufs dead
  const int r0 = (lane >> 4) << 2;
  const int cc = lane & 15;
#pragma unroll
  for (int j = 0; j < 2; ++j) {
    const int ml = wr * 16 + r0;
    const int nl = wc * 32 + j * 16 + cc;
#pragma unroll
    for (int r = 0; r < 4; ++r)
      sacc[(ml + r) * 68 + nl] = acc[j][r];
  }
  __syncthreads();

  // ---- cell: 32 batch x 16 j's; gates i,f,g,o = interleaved cols 4j+0..3
  for (int it = tid; it < 512; it += 256) {
    const int bl = it >> 4;                 // local batch 0..31
    const int jl = it & 15;                 // local j 0..15
    const int b  = m0 + bl;
    const int jg = (n0 >> 2) + jl;          // global j
    const float4 hw = *(const float4*)&sacc[bl * 68 + jl * 4];
    const u16x4 xq = *(const u16x4*)&XW_b[(size_t)b * GATES + n0 + jl * 4];
    const float gi = bf2f(xq.x) + hw.x;
    const float gf = bf2f(xq.y) + hw.y;
    const float gg = bf2f(xq.z) + hw.z;
    const float go = bf2f(xq.w) + hw.w;
    const int cidx = b * HID + jg;
    const float cp = cbuf[cidx];
    const float cv = sigm(gf) * cp + sigm(gi) * tanhf(gg);
    const float h  = tanhf(sigm(go) * tanhf(cv));
    cbuf[cidx]   = cv;
    hs_out[cidx] = f2bf(h);
  }
}

// ---------------- first step: gates = XW' only (biases included) ----------------
__global__ void cell_first(const u16* __restrict__ XW,
                           float* __restrict__ cbuf,
                           u16* __restrict__ hs_out) {
  int it = blockIdx.x * blockDim.x + threadIdx.x;   // 256*1536 items
  int b = it / HID;
  int j = it - b * HID;
  const u16x4 xq = *(const u16x4*)&XW[(size_t)b * GATES + 4 * j];
  const float cv = sigm(bf2f(xq.x)) * tanhf(bf2f(xq.z));
  const float h  = tanhf(sigm(bf2f(xq.w)) * tanhf(cv));
  cbuf[it]   = cv;
  hs_out[it] = f2bf(h);
}

// ---------------- final: out[b,n,o] = relu(out2[b,n,:]) @ lin_W^T + lin_b ----------------
__global__ __launch_bounds__(256) void final_k(const u16* __restrict__ hs,
                                               const float* __restrict__ lin_W,
                                               const float* __restrict__ lin_b,
                                               float* __restrict__ out) {
  __shared__ float Wsh[12 * 36];
  __shared__ float bsh[12];
  for (int i = threadIdx.x; i < 12 * 36; i += blockDim.x) Wsh[i] = lin_W[i];
  if (threadIdx.x < 12) bsh[threadIdx.x] = lin_b[threadIdx.x];
  __syncthreads();

  int idx = blockIdx.x * blockDim.x + threadIdx.x;
  int b = idx >> 9;
  int n = idx & 511;

  float acc[12];
#pragma unroll
  for (int o = 0; o < 12; ++o) acc[o] = bsh[o];

#pragma unroll
  for (int kk = 0; kk < 3; ++kk)
#pragma unroll
    for (int f = 0; f < 12; ++f) {
      float v = bf2f(hs[(size_t)(f * BSZ + b) * HID + 3 * n + kk]);
      v = fmaxf(v, 0.0f);
      int j = 12 * kk + f;
#pragma unroll
      for (int o = 0; o < 12; ++o) acc[o] += v * Wsh[o * 36 + j];
    }

#pragma unroll
  for (int o = 0; o < 12; ++o) out[(size_t)idx * 12 + o] = acc[o];
}

extern "C" void kernel_launch(void* const* d_in, const int* in_sizes, int n_in,
                              void* d_out, int out_size, void* d_ws, size_t ws_size,
                              hipStream_t stream) {
  (void)in_sizes; (void)n_in; (void)out_size; (void)ws_size;
  const float* X     = (const float*)d_in[1];
  const float* W_ih  = (const float*)d_in[2];
  const float* W_hh  = (const float*)d_in[3];
  const float* b_ih  = (const float*)d_in[4];
  const float* b_hh  = (const float*)d_in[5];
  const float* lin_W = (const float*)d_in[6];
  const float* lin_b = (const float*)d_in[7];
  float* out = (float*)d_out;

  char* p = (char*)d_ws;
  u16*   Ax   = (u16*)p;   p += (size_t)MROWS * INSZ * 2;
  u16*   Wihb = (u16*)p;   p += (size_t)GATES * INSZ * 2;
  u16*   Whhb = (u16*)p;   p += (size_t)GATES * HID * 2;
  u16*   XW   = (u16*)p;   p += (size_t)MROWS * GATES * 2;   // bf16 gates
  float* cbuf = (float*)p; p += (size_t)BSZ * HID * 4;
  u16*   hs   = (u16*)p;   p += (size_t)FF * BSZ * HID * 2;  // bf16 h ring + output

  hipFuncSetAttribute((const void*)gemm8p,
                      hipFuncAttributeMaxDynamicSharedMemorySize, LDS_TOTAL);

  // 1) convert weights (gate-interleaved rows) + pack X
  cvt_perm<<<(GATES * (INSZ / 4)) / 256, 256, 0, stream>>>(W_ih, Wihb, INSZ / 4);
  cvt_perm<<<(GATES * (HID / 4)) / 256, 256, 0, stream>>>(W_hh, Whhb, HID / 4);
  pack_x4<<<(BSZ * INSZ / 4) / 256, 256, 0, stream>>>(X, Ax);

  // 2) hoisted input GEMM: XW (bf16, interleaved cols) = Ax @ Wihb^T + biases
  gemm8p<<<256, 512, LDS_TOTAL, stream>>>(Ax, Wihb, b_ih, b_hh, XW,
                                          MROWS, GATES, INSZ);

  // 3) recurrence: fused GEMM+cell per step; h ring = bf16 hs slices
  const size_t S = (size_t)BSZ * HID;
  cell_first<<<(BSZ * HID) / 256, 256, 0, stream>>>(XW, cbuf, hs);
  for (int f = 1; f < FF; ++f) {
    gemm_cell<<<768, 256, 0, stream>>>(
        hs + (f - 1) * S, Whhb, XW + (size_t)f * BSZ * GATES, cbuf, hs + f * S);
  }

  // 4) final linear
  final_k<<<(BSZ * NN) / 256, 256, 0, stream>>>(hs, lin_W, lin_b, out);
}